// Round 5
// baseline (638.138 us; speedup 1.0000x reference)
//
#include <hip/hip_runtime.h>

// CrossScaleAttention on MI355X — round 10.
// R9 post-mortem: spill-free BM=64 -> 358us (-21%), FETCH 12.5MB. V-line
// model confirmed: V tile read once per block per iter; 16 lines/instr is
// irreducible (64 lanes x 16B); lever = fewer blocks, more q each.
// R10: BM=128 via 8-wave (512-thread) blocks, per-wave acc stays 36 f32x4:
//   score: wave w owns py-row w of 8 (54 MFMA/iter, unchanged shape)
//   PV: wave (mg=w>>2, ng=w&3): 64-q half mg x 144-n quarter ng
//   mg-paired waves read IDENTICAL V addresses -> 2nd read hits L1
//   (27.6KB/ng slice < 32KB L1). Per-CU line demand halves: 1 blk x 1728.
// Total lines 23.9M -> 11.9M. LDS 96KB -> 1 blk/CU, 2 waves/SIMD (same TLP).
// Per-wave regs identical to R9 -> same spill-free fit. Grid nb*72 = 288.
// Pre-committed: ~200-240us => confirmed; ~350 + clean FETCH => lever
// exhausted, ablation probe next; FETCH balloons => spill, revert R9.
//
// Workspace (101,246,976 B; known-good >= 105.6 MB):
//   xf16 : [4][98][98][32] fp16 match_input, zero halo        2,458,624
//   rkl  : [4][50][50][32] fp16 ref, zero halo                  640,000
//   ef32 : [4][50][50][64] f32 embed_w, zero halo             2,560,000
//   vtp  : [4][576][2304] bf16 V^T (n=tap*64+c, l=ly*48+lx)  10,616,832
//   invn : [4][2304] f32 10/max(norm,1e-4)                       36,864
//   Z    : [nb][9216][576] f32                            nb*21,233,664

typedef unsigned short u16;
typedef __attribute__((ext_vector_type(8))) short short8;      // 8 bf16
typedef __attribute__((ext_vector_type(8))) _Float16 half8;    // 8 fp16
typedef __attribute__((ext_vector_type(4))) float f32x4;

__device__ __forceinline__ u16 f2bf(float f) {
    unsigned u = __float_as_uint(f);
    unsigned r = (u + 0x7FFFu + ((u >> 16) & 1u)) >> 16;   // RNE
    return (u16)r;
}
__device__ __forceinline__ float bf2f(u16 h) {
    return __uint_as_float(((unsigned)h) << 16);
}
__device__ __forceinline__ u16 f2h(float f) {
    _Float16 h = (_Float16)f;           // v_cvt_f16_f32 (RNE)
    u16 u; __builtin_memcpy(&u, &h, 2); return u;
}
__device__ __forceinline__ float h2f(u16 u) {
    _Float16 h; __builtin_memcpy(&h, &u, 2); return (float)h;
}

// ---------------------------------------------------------------- zero fill
__global__ void kzero(float4* p, long n) {
    long i = (long)blockIdx.x * blockDim.x + threadIdx.x;
    long st = (long)gridDim.x * blockDim.x;
    float4 z; z.x = 0.f; z.y = 0.f; z.z = 0.f; z.w = 0.f;
    for (; i < n; i += st) p[i] = z;
}

// ------------------------------------------------- match_input -> xf16
__global__ void kmatch(const float* __restrict__ input, const float* __restrict__ w1,
                       const float* __restrict__ b1, const float* __restrict__ a1,
                       u16* __restrict__ xf16) {
    __shared__ float xl[64 * 96];
    __shared__ float wl[32 * 65];
    int b = blockIdx.x / 96, y = blockIdx.x % 96;
    int tid = threadIdx.x;
    for (int i = tid; i < 64 * 96; i += 256) {
        int ci = i / 96, xx = i % 96;
        xl[i] = input[(((b * 64 + ci) * 96) + y) * 96 + xx];
    }
    for (int i = tid; i < 2048; i += 256) wl[(i >> 6) * 65 + (i & 63)] = w1[i];
    __syncthreads();
    float aa = a1[0];
    for (int o = tid; o < 96 * 32; o += 256) {
        int xx = o >> 5, c = o & 31;
        float acc = b1[c];
        #pragma unroll
        for (int ci = 0; ci < 64; ci++) acc = fmaf(xl[ci * 96 + xx], wl[c * 65 + ci], acc);
        float v = acc >= 0.f ? acc : aa * acc;
        xf16[((b * 98 + y + 1) * 98 + (xx + 1)) * 32 + c] = f2h(v);
    }
}

// --------------------- small -> ef32 (embed, f32) + rkl fp16 (ref)
__global__ void ksmall(const float* __restrict__ small, const float* __restrict__ wasm,
                       const float* __restrict__ basm, const float* __restrict__ aasm,
                       const float* __restrict__ wm2, const float* __restrict__ bm2,
                       const float* __restrict__ am2,
                       float* __restrict__ ef32, u16* __restrict__ rkl) {
    __shared__ float sl[64 * 48];
    __shared__ float wa[64 * 65];
    __shared__ float wm[32 * 65];
    int b = blockIdx.x / 48, y = blockIdx.x % 48;
    int tid = threadIdx.x;
    for (int i = tid; i < 64 * 48; i += 256) {
        int ci = i / 48, xx = i % 48;
        sl[i] = small[(((b * 64 + ci) * 48) + y) * 48 + xx];
    }
    for (int i = tid; i < 4096; i += 256) wa[(i >> 6) * 65 + (i & 63)] = wasm[i];
    for (int i = tid; i < 2048; i += 256) wm[(i >> 6) * 65 + (i & 63)] = wm2[i];
    __syncthreads();
    float ae = aasm[0], ar = am2[0];
    for (int o = tid; o < 48 * 64; o += 256) {            // embed_w
        int xx = o >> 6, c = o & 63;
        float acc = basm[c];
        #pragma unroll
        for (int ci = 0; ci < 64; ci++) acc = fmaf(sl[ci * 48 + xx], wa[c * 65 + ci], acc);
        float v = acc >= 0.f ? acc : ae * acc;
        ef32[((b * 50 + y + 1) * 50 + (xx + 1)) * 64 + c] = v;
    }
    for (int o = tid; o < 48 * 32; o += 256) {            // ref -> rkl fp16
        int xx = o >> 5, c = o & 31;
        float acc = bm2[c];
        #pragma unroll
        for (int ci = 0; ci < 64; ci++) acc = fmaf(sl[ci * 48 + xx], wm[c * 65 + ci], acc);
        float v = acc >= 0.f ? acc : ar * acc;
        rkl[((b * 50 + y + 1) * 50 + (xx + 1)) * 32 + c] = f2h(v);
    }
}

// ------------------------------------------------------------ invnorm per key
__global__ void kinvnorm(const u16* __restrict__ rkl, float* __restrict__ invn) {
    int idx = blockIdx.x * 256 + threadIdx.x;   // 9216 exact
    int b = idx / 2304, l = idx % 2304;
    int ly = l / 48, lx = l % 48;
    float s = 0.f;
    for (int ty = 0; ty < 3; ty++)
        for (int tx = 0; tx < 3; tx++) {
            int base = ((b * 50 + ly + ty) * 50 + (lx + tx)) * 32;
            #pragma unroll
            for (int c = 0; c < 32; c++) {
                float v = h2f(rkl[base + c]);
                s = fmaf(v, v, s);
            }
        }
    invn[idx] = 10.f / fmaxf(sqrtf(s), 1e-4f);   // SCALE folded in
}

// ------------------------------------------------------------- pack V^T bf16
__global__ void kvtp(const float* __restrict__ ef32, u16* __restrict__ vtp) {
    int bi = blockIdx.x;
    int b = bi / 576, n = bi % 576;
    int t = n >> 6, c = n & 63;
    int ty = t / 3, tx = t % 3;
    const float* eb = ef32 + (size_t)b * 50 * 50 * 64 + c;
    u16* vo = vtp + (size_t)(b * 576 + n) * 2304;
    for (int l = threadIdx.x; l < 2304; l += 256) {
        int ly = l / 48, lx = l - ly * 48;
        vo[l] = f2bf(eb[((ly + ty) * 50 + (lx + tx)) * 64]);
    }
}

// ---------------------------------------------- async Ks staging (12800 B)
// 512-thread version: 800 chunks of 16B. Wave-uniform LDS base + lane*16.
__device__ __forceinline__ void stage_ks(const u16* __restrict__ src, u16* dst, int tid) {
    __builtin_amdgcn_global_load_lds(
        (const __attribute__((address_space(1))) void*)(src + (size_t)tid * 8),
        (__attribute__((address_space(3))) void*)(dst + (size_t)(tid & ~63) * 8),
        16, 0, 0);
    if (tid < 288)   // tail: chunks 512..799
        __builtin_amdgcn_global_load_lds(
            (const __attribute__((address_space(1))) void*)(src + (size_t)(tid + 512) * 8),
            (__attribute__((address_space(3))) void*)(dst + (size_t)((tid & ~63) + 512) * 8),
            16, 0, 0);
}

// ------------------------------------------------------------- fused score+PV
// grid = nb*72; block = 512 (8 waves). BM=128 queries (8 py-rows x 16 px),
// BN=96 keys/iter, 24 iters. Score: wave w owns py-row w (2 kh x 27 MFMA).
// PV: wave (mg=w>>2, ng=w&3): m-tiles mg*4..+3, n-cols ng*144 (acc[4][9]).
// One counted-vmcnt barrier per iter (vmcnt(9): drains Ks DMA, keeps 9 V
// loads in flight). Q in LDS; per-wave regs identical to R9 (spill-free).
__launch_bounds__(512, 2)
__global__ void kfused4(const u16* __restrict__ xf16, const u16* __restrict__ rkl,
                        const u16* __restrict__ vtp, const float* __restrict__ invn,
                        float* __restrict__ Z, int b0, int nb) {
    __shared__ u16 Ks[2][6400];       // 25600 B: dbuf, 4 halo rows x [50 px][32 c] fp16
    __shared__ u16 Pl[2][12288];      // 49152 B: dbuf, [8 mtile][3 kb][16 m][32 kc]
    __shared__ float Ln[2304];        //  9216 B: invn for this batch
    __shared__ u16 Qs[10 * 18 * 32];  // 11520 B: Q rows pyb..pyb+9, px0..px0+17
    __shared__ float llds[8][16];     //   512 B  -> 96000 B total

    int tid = threadIdx.x;
    int w = tid >> 6, lane = tid & 63, l15 = lane & 15, quad = lane >> 4;
    int mg = w >> 2, ng = w & 3;
    int bi = blockIdx.x, brel, t;
    if (nb == 4) { brel = bi & 3; t = bi >> 2; }
    else         { brel = 0; t = bi; }
    int b = b0 + brel;
    int px0 = (t % 6) * 16, pyb = (t / 6) * 8;     // 6 x-tiles x 12 y-groups = 72

    const u16* xb = xf16 + (size_t)b * 98 * 98 * 32;
    const u16* rb = rkl + (size_t)b * 50 * 50 * 32;
    const float* invb = invn + b * 2304;
    const u16* vw = vtp + (size_t)b * 576 * 2304 + (size_t)(ng * 144 + l15) * 2304 + quad * 8;

    stage_ks(rb, Ks[0], tid);       // async; drained by the prologue barrier
    __builtin_amdgcn_sched_barrier(0);

    // invn -> LDS (once)
    for (int i = tid; i < 576; i += 512)
        ((float4*)Ln)[i] = ((const float4*)invb)[i];

    // Q tile -> LDS (once): 10 rows x 18 px x 32 c fp16 = 180 cells x 4 chunks
    for (int u = tid; u < 720; u += 512) {
        int cell = u >> 2, ch = u & 3;
        int r = cell / 18, p = cell % 18;
        *(short8*)&Qs[(r * 18 + p) * 32 + ch * 8] =
            *(const short8*)(xb + (((pyb + r) * 98) + (px0 + p)) * 32 + ch * 8);
    }

    f32x4 acc[36];
    #pragma unroll
    for (int i = 0; i < 36; i++) acc[i] = (f32x4)0.f;
    float lacc[4] = {0.f, 0.f, 0.f, 0.f};

    __syncthreads();   // prologue: full drain (Ks[0] DMA + Ln + Qs staged)

    short8 vv[9];

    for (int it = 0; it < 24; ++it) {
        int ly0 = it * 2;
        int cur = it & 1;

        // ---- 1. DMA next Ks (oldest VMEM of this iter — vmcnt(9) relies on it)
        if (it < 23) stage_ks(rb + (ly0 + 2) * 1600, Ks[cur ^ 1], tid);
        __builtin_amdgcn_sched_barrier(0);   // pin DMA-first issue order

        // ---- 2. V ks=0 loads (9; ride across the barrier into PV)
        const u16* vit = vw + it * 96;
        #pragma unroll
        for (int nt = 0; nt < 9; ++nt) vv[nt] = *(const short8*)(vit + (size_t)nt * 36864);

        // ---- 3+4. score + exp for both key halves of this wave's q-tile
        const u16* Kc = Ks[cur];
        u16* Pc = Pl[cur];
        #pragma unroll
        for (int kh = 0; kh < 2; ++kh) {
            f32x4 sf[3];
            #pragma unroll
            for (int i = 0; i < 3; i++) sf[i] = (f32x4)0.f;
            __builtin_amdgcn_s_setprio(1);
            #pragma unroll
            for (int ty = 0; ty < 3; ++ty)
                #pragma unroll
                for (int tx = 0; tx < 3; ++tx) {
                    half8 a = *(const half8*)&Qs[((w + ty) * 18 + (l15 + tx)) * 32 + quad * 8];
                    #pragma unroll
                    for (int lxo = 0; lxo < 3; ++lxo) {
                        half8 bb = *(const half8*)&Kc[(kh + ty) * 1600 + (lxo * 16 + l15 + tx) * 32 + quad * 8];
                        sf[lxo] = __builtin_amdgcn_mfma_f32_16x16x32_f16(a, bb, sf[lxo], 0, 0, 0);
                    }
                }
            __builtin_amdgcn_s_setprio(0);
            #pragma unroll
            for (int lxo = 0; lxo < 3; ++lxo) {
                float invs = Ln[(ly0 + kh) * 48 + lxo * 16 + l15];
                int k = kh * 48 + lxo * 16 + l15;
                int kb = k >> 5;
                int kc = (k & 31) ^ (quad << 3);   // XOR swizzle by quad (= m>>2)
                #pragma unroll
                for (int r = 0; r < 4; ++r) {
                    float p = __expf(sf[lxo][r] * invs);
                    u16 h = f2bf(p);
                    Pc[(w * 3 + kb) * 512 + (quad * 4 + r) * 32 + kc] = h;
                    lacc[r] += bf2f(h);   // l exactly as the PV MFMA sees P
                }
            }
        }

        // ---- 5. counted-vmcnt barrier: Pl visible (lgkm 0) + Ks DMA landed
        // (vmcnt<=9: the 9 newer vv loads may stay in flight).
        asm volatile("s_waitcnt vmcnt(9) lgkmcnt(0)" ::: "memory");
        __builtin_amdgcn_s_barrier();
        __builtin_amdgcn_sched_barrier(0);

        // ---- 6. PV: O[mg-half 64q, ng-quarter 144n] += P @ V, bf16
        const u16* Pr = Pl[cur];
        int pcol = l15 * 32 + ((quad ^ (l15 >> 2)) & 3) * 8;
        __builtin_amdgcn_s_setprio(1);
        #pragma unroll
        for (int ks = 0; ks < 3; ++ks) {
            short8 pa0 = *(const short8*)&Pr[((mg * 4 + 0) * 3 + ks) * 512 + pcol];
            short8 pa1 = *(const short8*)&Pr[((mg * 4 + 1) * 3 + ks) * 512 + pcol];
            #pragma unroll
            for (int nt = 0; nt < 9; ++nt) {
                short8 vn = vv[nt];
                acc[0 * 9 + nt] = __builtin_amdgcn_mfma_f32_16x16x32_bf16(pa0, vn, acc[0 * 9 + nt], 0, 0, 0);
                acc[1 * 9 + nt] = __builtin_amdgcn_mfma_f32_16x16x32_bf16(pa1, vn, acc[1 * 9 + nt], 0, 0, 0);
            }
            pa0 = *(const short8*)&Pr[((mg * 4 + 2) * 3 + ks) * 512 + pcol];
            pa1 = *(const short8*)&Pr[((mg * 4 + 3) * 3 + ks) * 512 + pcol];
            #pragma unroll
            for (int nt = 0; nt < 9; ++nt) {
                short8 vn = vv[nt];
                acc[2 * 9 + nt] = __builtin_amdgcn_mfma_f32_16x16x32_bf16(pa0, vn, acc[2 * 9 + nt], 0, 0, 0);
                acc[3 * 9 + nt] = __builtin_amdgcn_mfma_f32_16x16x32_bf16(pa1, vn, acc[3 * 9 + nt], 0, 0, 0);
                if (ks < 2)   // reload right after last use; covered by rest of phase
                    vv[nt] = *(const short8*)(vit + (size_t)nt * 36864 + (ks + 1) * 32);
            }
        }
        __builtin_amdgcn_s_setprio(0);
    }

    // ---- epilogue: reduce l over l15; share per-row l via LDS; Z = O/(6l)
    #pragma unroll
    for (int r = 0; r < 4; ++r) {
        float v = lacc[r];
        v += __shfl_xor(v, 1);
        v += __shfl_xor(v, 2);
        v += __shfl_xor(v, 4);
        v += __shfl_xor(v, 8);
        lacc[r] = v;
    }
    if (l15 == 0) {
        #pragma unroll
        for (int r = 0; r < 4; ++r)
            llds[w][quad * 4 + r] = lacc[r];
    }
    __syncthreads();
    float* Zb = Z + (size_t)brel * 9216 * 576;
    #pragma unroll
    for (int mt = 0; mt < 4; ++mt) {
        int m8 = mg * 4 + mt;
        #pragma unroll
        for (int r = 0; r < 4; ++r) {
            int q = (pyb + m8) * 96 + px0 + quad * 4 + r;
            float rl = 1.0f / (llds[m8][quad * 4 + r] * 6.0f);
            float* zr = Zb + (size_t)q * 576 + ng * 144;
            #pragma unroll
            for (int nt = 0; nt < 9; ++nt)
                __builtin_nontemporal_store(acc[mt * 9 + nt][r] * rl, zr + nt * 16 + l15);
        }
    }
}

// ------------------------------------------------------------- gather (Z -> out)
__global__ void kgather(const float* __restrict__ Z, float* __restrict__ out, int b0) {
    __shared__ float zb[2 * 9 * 580];   // 41760 B
    int bi = blockIdx.x;                // nb*96*12
    int brel = bi / (96 * 12);
    int rem = bi % (96 * 12);
    int b = b0 + brel;
    int q = rem / 12, xt = rem % 12;
    int ox0 = xt * 16, p0 = ox0 >> 1;
    const float* Zb = Z + (size_t)brel * 9216 * 576;
    int tid = threadIdx.x;
    for (int id = tid; id < 2592; id += 256) {
        int pi = id / 1296, r2 = id % 1296;
        int pxi = r2 / 144, n4 = r2 % 144;
        int py = q + pi; if (py > 95) py = 95;
        int px = p0 + pxi; if (px > 95) px = 95;
        *(float4*)&zb[(pi * 9 + pxi) * 580 + n4 * 4] =
            *(const float4*)&Zb[(size_t)(py * 96 + px) * 576 + n4 * 4];
    }
    __syncthreads();
    int xi = tid & 15, cq = tid >> 4;
    int ox = ox0 + xi;
    bool oxv = ox <= 190;
    int ntx, txl[2], pxl[2];
    if (xi & 1) { ntx = 2; txl[0] = 0; pxl[0] = (xi + 1) >> 1; txl[1] = 2; pxl[1] = (xi - 1) >> 1; }
    else        { ntx = 1; txl[0] = 1; pxl[0] = xi >> 1; txl[1] = 1; pxl[1] = xi >> 1; }
    int oy0 = 2 * q;
    #pragma unroll
    for (int ck = 0; ck < 4; ++ck) {
        int c = cq + ck * 16;
        float v0 = 0.f, v1 = 0.f;
        for (int j = 0; j < ntx; ++j) {
            int tx = txl[j], pxi = pxl[j];
            v0 += zb[(0 * 9 + pxi) * 580 + (3 + tx) * 64 + c];
            v1 += zb[(1 * 9 + pxi) * 580 + (0 + tx) * 64 + c];
            v1 += zb[(0 * 9 + pxi) * 580 + (6 + tx) * 64 + c];
        }
        if (oxv) {
            float* o = out + (((size_t)(b * 64 + c) * 191 + oy0) * 191 + ox);
            *o = v0;
            if (q < 95) *(o + 191) = v1;
        }
    }
}

// --------------------------------------------------------------------- host
extern "C" void kernel_launch(void* const* d_in, const int* in_sizes, int n_in,
                              void* d_out, int out_size, void* d_ws, size_t ws_size,
                              hipStream_t stream) {
    const float* input = (const float*)d_in[0];
    const float* small = (const float*)d_in[1];
    const float* w1 = (const float*)d_in[2];
    const float* b1 = (const float*)d_in[3];
    const float* a1 = (const float*)d_in[4];
    const float* w2 = (const float*)d_in[5];
    const float* b2 = (const float*)d_in[6];
    const float* a2 = (const float*)d_in[7];
    const float* wa = (const float*)d_in[8];
    const float* ba = (const float*)d_in[9];
    const float* aa = (const float*)d_in[10];

    char* ws = (char*)d_ws;
    u16* xf16 = (u16*)(ws + 0);             //  2,458,624
    u16* rkl = (u16*)(ws + 2458624);        //    640,000
    float* ef = (float*)(ws + 3098624);     //  2,560,000
    u16* vtp = (u16*)(ws + 5658624);        // 10,616,832
    float* invn = (float*)(ws + 16275456);  //     36,864
    const size_t PREP = 16312320;
    float* Zbuf = (float*)(ws + PREP);      // nb*21,233,664
    float* out = (float*)d_out;

    int nb = (ws_size >= (size_t)101246976) ? 4 : 1;

    kzero<<<1024, 256, 0, stream>>>((float4*)ws, 5658624 / 16);   // halo'd arrays
    kmatch<<<384, 256, 0, stream>>>(input, w1, b1, a1, xf16);
    ksmall<<<192, 256, 0, stream>>>(small, wa, ba, aa, w2, b2, a2, ef, rkl);
    kinvnorm<<<36, 256, 0, stream>>>(rkl, invn);
    kvtp<<<2304, 256, 0, stream>>>(ef, vtp);

    for (int b0 = 0; b0 < 4; b0 += nb) {
        kfused4<<<nb * 72, 512, 0, stream>>>(xf16, rkl, vtp, invn, Zbuf, b0, nb);
        kgather<<<nb * 1152, 256, 0, stream>>>(Zbuf, out, b0);
    }
}

// Round 6
// 589.365 us; speedup vs baseline: 1.0828x; 1.0828x over previous
//
#include <hip/hip_runtime.h>

// CrossScaleAttention on MI355X — round 11.
// R10 post-mortem: BM=128/1-block-per-CU REGRESSED (457 vs 358us, FETCH
// clean) -> V-line demand was NOT R9's binder; the 2 independent blocks/CU
// in R9 are load-bearing (barrier/stall overlap partner). Reverted to R9.
// R9 slot budget (~15.9Kcy): LDS wave-reads ~5.4K (score 72/wave/iter),
// lines ~3.9K, MFMA ~1.6K, VALU ~1K -> serialized phases, partial overlap.
// R11 (R9 + two targeted cuts, structure/sync untouched):
//   (a) row-major score: kh=0 rows{0,1,2} and kh=1 rows{1,2,3} share rows
//       1,2 at identical (tx,lxo) addresses -> compute both kh in one pass
//       over rows 0..3: bb reads 54->36/wave/iter, bit-identical MFMA order.
//   (b) kvtp rewrite: was 256B-stride gather (4B/64B line, ~340MB lines);
//       now block per (b,ly): LDS-stage 3 ef rows, coalesced bf16 writes.
// Pre-committed: kfused ~325-340 => LDS-cut confirmed; FETCH balloons =>
// sf0/sf1 spill, revert (a); kfused >=350 => null, go producer/consumer.
//
// Workspace (101,246,976 B; known-good >= 105.6 MB):
//   xf16 : [4][98][98][32] fp16 match_input, zero halo        2,458,624
//   rkl  : [4][50][50][32] fp16 ref, zero halo                  640,000
//   ef32 : [4][50][50][64] f32 embed_w, zero halo             2,560,000
//   vtp  : [4][576][2304] bf16 V^T (n=tap*64+c, l=ly*48+lx)  10,616,832
//   invn : [4][2304] f32 10/max(norm,1e-4)                       36,864
//   Z    : [nb][9216][576] f32                            nb*21,233,664

typedef unsigned short u16;
typedef __attribute__((ext_vector_type(8))) short short8;      // 8 bf16
typedef __attribute__((ext_vector_type(8))) _Float16 half8;    // 8 fp16
typedef __attribute__((ext_vector_type(4))) float f32x4;

__device__ __forceinline__ u16 f2bf(float f) {
    unsigned u = __float_as_uint(f);
    unsigned r = (u + 0x7FFFu + ((u >> 16) & 1u)) >> 16;   // RNE
    return (u16)r;
}
__device__ __forceinline__ float bf2f(u16 h) {
    return __uint_as_float(((unsigned)h) << 16);
}
__device__ __forceinline__ u16 f2h(float f) {
    _Float16 h = (_Float16)f;           // v_cvt_f16_f32 (RNE)
    u16 u; __builtin_memcpy(&u, &h, 2); return u;
}
__device__ __forceinline__ float h2f(u16 u) {
    _Float16 h; __builtin_memcpy(&h, &u, 2); return (float)h;
}

// ---------------------------------------------------------------- zero fill
__global__ void kzero(float4* p, long n) {
    long i = (long)blockIdx.x * blockDim.x + threadIdx.x;
    long st = (long)gridDim.x * blockDim.x;
    float4 z; z.x = 0.f; z.y = 0.f; z.z = 0.f; z.w = 0.f;
    for (; i < n; i += st) p[i] = z;
}

// ------------------------------------------------- match_input -> xf16
__global__ void kmatch(const float* __restrict__ input, const float* __restrict__ w1,
                       const float* __restrict__ b1, const float* __restrict__ a1,
                       u16* __restrict__ xf16) {
    __shared__ float xl[64 * 96];
    __shared__ float wl[32 * 65];
    int b = blockIdx.x / 96, y = blockIdx.x % 96;
    int tid = threadIdx.x;
    for (int i = tid; i < 64 * 96; i += 256) {
        int ci = i / 96, xx = i % 96;
        xl[i] = input[(((b * 64 + ci) * 96) + y) * 96 + xx];
    }
    for (int i = tid; i < 2048; i += 256) wl[(i >> 6) * 65 + (i & 63)] = w1[i];
    __syncthreads();
    float aa = a1[0];
    for (int o = tid; o < 96 * 32; o += 256) {
        int xx = o >> 5, c = o & 31;
        float acc = b1[c];
        #pragma unroll
        for (int ci = 0; ci < 64; ci++) acc = fmaf(xl[ci * 96 + xx], wl[c * 65 + ci], acc);
        float v = acc >= 0.f ? acc : aa * acc;
        xf16[((b * 98 + y + 1) * 98 + (xx + 1)) * 32 + c] = f2h(v);
    }
}

// --------------------- small -> ef32 (embed, f32) + rkl fp16 (ref)
__global__ void ksmall(const float* __restrict__ small, const float* __restrict__ wasm,
                       const float* __restrict__ basm, const float* __restrict__ aasm,
                       const float* __restrict__ wm2, const float* __restrict__ bm2,
                       const float* __restrict__ am2,
                       float* __restrict__ ef32, u16* __restrict__ rkl) {
    __shared__ float sl[64 * 48];
    __shared__ float wa[64 * 65];
    __shared__ float wm[32 * 65];
    int b = blockIdx.x / 48, y = blockIdx.x % 48;
    int tid = threadIdx.x;
    for (int i = tid; i < 64 * 48; i += 256) {
        int ci = i / 48, xx = i % 48;
        sl[i] = small[(((b * 64 + ci) * 48) + y) * 48 + xx];
    }
    for (int i = tid; i < 4096; i += 256) wa[(i >> 6) * 65 + (i & 63)] = wasm[i];
    for (int i = tid; i < 2048; i += 256) wm[(i >> 6) * 65 + (i & 63)] = wm2[i];
    __syncthreads();
    float ae = aasm[0], ar = am2[0];
    for (int o = tid; o < 48 * 64; o += 256) {            // embed_w
        int xx = o >> 6, c = o & 63;
        float acc = basm[c];
        #pragma unroll
        for (int ci = 0; ci < 64; ci++) acc = fmaf(sl[ci * 48 + xx], wa[c * 65 + ci], acc);
        float v = acc >= 0.f ? acc : ae * acc;
        ef32[((b * 50 + y + 1) * 50 + (xx + 1)) * 64 + c] = v;
    }
    for (int o = tid; o < 48 * 32; o += 256) {            // ref -> rkl fp16
        int xx = o >> 5, c = o & 31;
        float acc = bm2[c];
        #pragma unroll
        for (int ci = 0; ci < 64; ci++) acc = fmaf(sl[ci * 48 + xx], wm[c * 65 + ci], acc);
        float v = acc >= 0.f ? acc : ar * acc;
        rkl[((b * 50 + y + 1) * 50 + (xx + 1)) * 32 + c] = f2h(v);
    }
}

// ------------------------------------------------------------ invnorm per key
__global__ void kinvnorm(const u16* __restrict__ rkl, float* __restrict__ invn) {
    int idx = blockIdx.x * 256 + threadIdx.x;   // 9216 exact
    int b = idx / 2304, l = idx % 2304;
    int ly = l / 48, lx = l % 48;
    float s = 0.f;
    for (int ty = 0; ty < 3; ty++)
        for (int tx = 0; tx < 3; tx++) {
            int base = ((b * 50 + ly + ty) * 50 + (lx + tx)) * 32;
            #pragma unroll
            for (int c = 0; c < 32; c++) {
                float v = h2f(rkl[base + c]);
                s = fmaf(v, v, s);
            }
        }
    invn[idx] = 10.f / fmaxf(sqrtf(s), 1e-4f);   // SCALE folded in
}

// ------------------------------------------------------------- pack V^T bf16
// R11: block per (b, ly). Stage ef rows ly..ly+2 in LDS (coalesced reads),
// write each n-row's 48-element segment contiguously (coalesced 8B stores).
// Replaces the 256B-stride 4B-gather (was ~340MB of 64B-line traffic).
__global__ void kvtp(const float* __restrict__ ef32, u16* __restrict__ vtp) {
    __shared__ float el[3][50 * 64];    // 38400 B
    int bi = blockIdx.x;                // 4*48
    int b = bi / 48, ly = bi % 48;
    const float* eb = ef32 + (size_t)b * 50 * 50 * 64;
    int tid = threadIdx.x;
    #pragma unroll
    for (int r = 0; r < 3; ++r)
        for (int i = tid; i < 800; i += 256)
            ((float4*)el[r])[i] = ((const float4*)(eb + (size_t)(ly + r) * 3200))[i];
    __syncthreads();
    u16* vo = vtp + (size_t)b * 576 * 2304 + (size_t)ly * 48;
    for (int n = tid; n < 576; n += 256) {
        int t = n >> 6, c = n & 63;
        int ty = t / 3, tx = t - ty * 3;
        u16* dst = vo + (size_t)n * 2304;
        const float* src = &el[ty][tx * 64 + c];
        #pragma unroll
        for (int g = 0; g < 12; ++g) {
            unsigned lo = (unsigned)f2bf(src[(g * 4 + 0) * 64]) |
                          ((unsigned)f2bf(src[(g * 4 + 1) * 64]) << 16);
            unsigned hi = (unsigned)f2bf(src[(g * 4 + 2) * 64]) |
                          ((unsigned)f2bf(src[(g * 4 + 3) * 64]) << 16);
            uint2 pk; pk.x = lo; pk.y = hi;
            *(uint2*)&dst[g * 4] = pk;   // 8B aligned: 2304*2B row stride, 96B base
        }
    }
}

// ---------------------------------------------- async Ks staging (12800 B)
__device__ __forceinline__ void stage_ks(const u16* __restrict__ src, u16* dst, int tid) {
    int wb = tid & ~63;   // wave-uniform LDS base
    #pragma unroll
    for (int k = 0; k < 3; ++k)
        __builtin_amdgcn_global_load_lds(
            (const __attribute__((address_space(1))) void*)(src + (size_t)(tid + k * 256) * 8),
            (__attribute__((address_space(3))) void*)(dst + (size_t)(wb + k * 256) * 8),
            16, 0, 0);
    if (tid < 32)   // tail: 800*16B total, lanes 0..31 of wave 0
        __builtin_amdgcn_global_load_lds(
            (const __attribute__((address_space(1))) void*)(src + (size_t)(tid + 768) * 8),
            (__attribute__((address_space(3))) void*)(dst + (size_t)768 * 8),
            16, 0, 0);
}

// ------------------------------------------------------------- fused score+PV
// grid = nb*144; block = 256 (4 waves). BM=64 queries (4 py-rows x 16 px),
// BN=96 keys/iter, 24 iters. Wave w: score for q-tile w (both key halves),
// PV for n-quarter w over all 64 q (acc[4][9]). Q tile in LDS.
// R11: row-major score — one pass over K rows 0..3 accumulates BOTH kh
// score tiles (rows 1,2 bb reads shared): 36 bb reads vs 54, identical
// MFMA accumulation order (bit-identical results).
__launch_bounds__(256, 2)
__global__ void kfused3(const u16* __restrict__ xf16, const u16* __restrict__ rkl,
                        const u16* __restrict__ vtp, const float* __restrict__ invn,
                        float* __restrict__ Z, int b0, int nb) {
    __shared__ u16 Ks[2][6400];     // 25600 B: dbuf, 4 halo rows x [50 px][32 c] fp16
    __shared__ u16 Pl[2][6144];     // 24576 B: dbuf, [4 mtile][3 kb][16 m][32 kc]
    __shared__ float Ln[2304];      //  9216 B: invn for this batch
    __shared__ u16 Qs[6 * 18 * 32]; //  6912 B: Q tile rows pyb..pyb+5, px0..px0+17
    __shared__ float llds[4][16];   //   256 B  -> 66560 B total

    int tid = threadIdx.x;
    int w = tid >> 6, lane = tid & 63, l15 = lane & 15, quad = lane >> 4;
    int bi = blockIdx.x, brel, t;
    if (nb == 4) { brel = bi & 3; t = bi >> 2; }
    else         { brel = 0; t = bi; }
    int b = b0 + brel;
    int px0 = (t % 6) * 16, pyb = (t / 6) * 4;     // 6 x-tiles x 24 y-groups = 144

    const u16* xb = xf16 + (size_t)b * 98 * 98 * 32;
    const u16* rb = rkl + (size_t)b * 50 * 50 * 32;
    const float* invb = invn + b * 2304;
    const u16* vw = vtp + (size_t)b * 576 * 2304 + (size_t)(w * 144 + l15) * 2304 + quad * 8;

    stage_ks(rb, Ks[0], tid);       // async; drained by the prologue barrier
    __builtin_amdgcn_sched_barrier(0);

    // invn -> LDS (once)
    for (int i = tid; i < 576; i += 256)
        ((float4*)Ln)[i] = ((const float4*)invb)[i];

    // Q tile -> LDS (once): 6 rows x 18 px x 32 c fp16 = 108 cells x 4 chunks
    for (int u = tid; u < 432; u += 256) {
        int cell = u >> 2, ch = u & 3;
        int r = cell / 18, p = cell % 18;
        *(short8*)&Qs[(r * 18 + p) * 32 + ch * 8] =
            *(const short8*)(xb + (((pyb + r) * 98) + (px0 + p)) * 32 + ch * 8);
    }

    f32x4 acc[36];
    #pragma unroll
    for (int i = 0; i < 36; i++) acc[i] = (f32x4)0.f;
    float lacc[4] = {0.f, 0.f, 0.f, 0.f};

    __syncthreads();   // prologue: full drain (Ks[0] DMA + Ln + Qs staged)

    short8 vv[9];

    for (int it = 0; it < 24; ++it) {
        int ly0 = it * 2;
        int cur = it & 1;

        // ---- 1. DMA next Ks (oldest VMEM of this iter — vmcnt(9) relies on it)
        if (it < 23) stage_ks(rb + (ly0 + 2) * 1600, Ks[cur ^ 1], tid);
        __builtin_amdgcn_sched_barrier(0);   // pin DMA-first issue order

        // ---- 2. V ks=0 loads (9; ride across the barrier into PV)
        const u16* vit = vw + it * 96;
        #pragma unroll
        for (int nt = 0; nt < 9; ++nt) vv[nt] = *(const short8*)(vit + (size_t)nt * 36864);

        // ---- 3+4. row-major score: both kh in one pass over K rows 0..3
        const u16* Kc = Ks[cur];
        u16* Pc = Pl[cur];
        f32x4 sf0[3], sf1[3];
        #pragma unroll
        for (int i = 0; i < 3; i++) { sf0[i] = (f32x4)0.f; sf1[i] = (f32x4)0.f; }

        __builtin_amdgcn_s_setprio(1);
        #pragma unroll
        for (int row = 0; row < 3; ++row)      // rows 0..2: kh0 (ty=row) + kh1 (ty=row-1)
            #pragma unroll
            for (int tx = 0; tx < 3; ++tx) {
                half8 a0 = *(const half8*)&Qs[((w + row) * 18 + (l15 + tx)) * 32 + quad * 8];
                half8 a1;
                if (row >= 1) a1 = *(const half8*)&Qs[((w + row - 1) * 18 + (l15 + tx)) * 32 + quad * 8];
                #pragma unroll
                for (int lxo = 0; lxo < 3; ++lxo) {
                    half8 bb = *(const half8*)&Kc[row * 1600 + (lxo * 16 + l15 + tx) * 32 + quad * 8];
                    sf0[lxo] = __builtin_amdgcn_mfma_f32_16x16x32_f16(a0, bb, sf0[lxo], 0, 0, 0);
                    if (row >= 1)
                        sf1[lxo] = __builtin_amdgcn_mfma_f32_16x16x32_f16(a1, bb, sf1[lxo], 0, 0, 0);
                }
            }
        __builtin_amdgcn_s_setprio(0);

        // exp for kh=0 (frees sf0 before row 3)
        #pragma unroll
        for (int lxo = 0; lxo < 3; ++lxo) {
            float invs = Ln[(ly0 + 0) * 48 + lxo * 16 + l15];
            int k = 0 * 48 + lxo * 16 + l15;
            int kb = k >> 5;
            int kc = (k & 31) ^ (quad << 3);
            #pragma unroll
            for (int r = 0; r < 4; ++r) {
                float p = __expf(sf0[lxo][r] * invs);
                u16 h = f2bf(p);
                Pc[(w * 3 + kb) * 512 + (quad * 4 + r) * 32 + kc] = h;
                lacc[r] += bf2f(h);
            }
        }

        __builtin_amdgcn_s_setprio(1);
        #pragma unroll
        for (int tx = 0; tx < 3; ++tx) {       // row 3: kh1 ty=2
            half8 a1 = *(const half8*)&Qs[((w + 2) * 18 + (l15 + tx)) * 32 + quad * 8];
            #pragma unroll
            for (int lxo = 0; lxo < 3; ++lxo) {
                half8 bb = *(const half8*)&Kc[3 * 1600 + (lxo * 16 + l15 + tx) * 32 + quad * 8];
                sf1[lxo] = __builtin_amdgcn_mfma_f32_16x16x32_f16(a1, bb, sf1[lxo], 0, 0, 0);
            }
        }
        __builtin_amdgcn_s_setprio(0);

        // exp for kh=1
        #pragma unroll
        for (int lxo = 0; lxo < 3; ++lxo) {
            float invs = Ln[(ly0 + 1) * 48 + lxo * 16 + l15];
            int k = 1 * 48 + lxo * 16 + l15;
            int kb = k >> 5;
            int kc = (k & 31) ^ (quad << 3);
            #pragma unroll
            for (int r = 0; r < 4; ++r) {
                float p = __expf(sf1[lxo][r] * invs);
                u16 h = f2bf(p);
                Pc[(w * 3 + kb) * 512 + (quad * 4 + r) * 32 + kc] = h;
                lacc[r] += bf2f(h);
            }
        }

        // ---- 5. counted-vmcnt barrier: Pl visible (lgkm 0) + Ks DMA landed
        // (vmcnt<=9: the 9 newer vv loads may stay in flight).
        asm volatile("s_waitcnt vmcnt(9) lgkmcnt(0)" ::: "memory");
        __builtin_amdgcn_s_barrier();
        __builtin_amdgcn_sched_barrier(0);

        // ---- 6. PV: O[64, this wave's 144 cols] += P[64,96] @ V[96,144], bf16
        const u16* Pr = Pl[cur];
        int pcol = l15 * 32 + ((quad ^ (l15 >> 2)) & 3) * 8;
        __builtin_amdgcn_s_setprio(1);
        #pragma unroll
        for (int ks = 0; ks < 3; ++ks) {
            short8 pa0 = *(const short8*)&Pr[(0 * 3 + ks) * 512 + pcol];
            short8 pa1 = *(const short8*)&Pr[(1 * 3 + ks) * 512 + pcol];
            #pragma unroll
            for (int nt = 0; nt < 9; ++nt) {
                short8 vn = vv[nt];
                acc[0 * 9 + nt] = __builtin_amdgcn_mfma_f32_16x16x32_bf16(pa0, vn, acc[0 * 9 + nt], 0, 0, 0);
                acc[1 * 9 + nt] = __builtin_amdgcn_mfma_f32_16x16x32_bf16(pa1, vn, acc[1 * 9 + nt], 0, 0, 0);
            }
            pa0 = *(const short8*)&Pr[(2 * 3 + ks) * 512 + pcol];
            pa1 = *(const short8*)&Pr[(3 * 3 + ks) * 512 + pcol];
            #pragma unroll
            for (int nt = 0; nt < 9; ++nt) {
                short8 vn = vv[nt];
                acc[2 * 9 + nt] = __builtin_amdgcn_mfma_f32_16x16x32_bf16(pa0, vn, acc[2 * 9 + nt], 0, 0, 0);
                acc[3 * 9 + nt] = __builtin_amdgcn_mfma_f32_16x16x32_bf16(pa1, vn, acc[3 * 9 + nt], 0, 0, 0);
                if (ks < 2)   // reload right after last use; covered by rest of phase
                    vv[nt] = *(const short8*)(vit + (size_t)nt * 36864 + (ks + 1) * 32);
            }
        }
        __builtin_amdgcn_s_setprio(0);
    }

    // ---- epilogue: reduce l over l15; share per-tile l via LDS; Z = O/(6l)
    #pragma unroll
    for (int r = 0; r < 4; ++r) {
        float v = lacc[r];
        v += __shfl_xor(v, 1);
        v += __shfl_xor(v, 2);
        v += __shfl_xor(v, 4);
        v += __shfl_xor(v, 8);
        lacc[r] = v;
    }
    if (l15 == 0) {
        #pragma unroll
        for (int r = 0; r < 4; ++r)
            llds[w][quad * 4 + r] = lacc[r];
    }
    __syncthreads();
    float* Zb = Z + (size_t)brel * 9216 * 576;
    #pragma unroll
    for (int mt = 0; mt < 4; ++mt) {
        #pragma unroll
        for (int r = 0; r < 4; ++r) {
            int q = (pyb + mt) * 96 + px0 + quad * 4 + r;
            float rl = 1.0f / (llds[mt][quad * 4 + r] * 6.0f);
            float* zr = Zb + (size_t)q * 576 + w * 144;
            #pragma unroll
            for (int nt = 0; nt < 9; ++nt)
                __builtin_nontemporal_store(acc[mt * 9 + nt][r] * rl, zr + nt * 16 + l15);
        }
    }
}

// ------------------------------------------------------------- gather (Z -> out)
__global__ void kgather(const float* __restrict__ Z, float* __restrict__ out, int b0) {
    __shared__ float zb[2 * 9 * 580];   // 41760 B
    int bi = blockIdx.x;                // nb*96*12
    int brel = bi / (96 * 12);
    int rem = bi % (96 * 12);
    int b = b0 + brel;
    int q = rem / 12, xt = rem % 12;
    int ox0 = xt * 16, p0 = ox0 >> 1;
    const float* Zb = Z + (size_t)brel * 9216 * 576;
    int tid = threadIdx.x;
    for (int id = tid; id < 2592; id += 256) {
        int pi = id / 1296, r2 = id % 1296;
        int pxi = r2 / 144, n4 = r2 % 144;
        int py = q + pi; if (py > 95) py = 95;
        int px = p0 + pxi; if (px > 95) px = 95;
        *(float4*)&zb[(pi * 9 + pxi) * 580 + n4 * 4] =
            *(const float4*)&Zb[(size_t)(py * 96 + px) * 576 + n4 * 4];
    }
    __syncthreads();
    int xi = tid & 15, cq = tid >> 4;
    int ox = ox0 + xi;
    bool oxv = ox <= 190;
    int ntx, txl[2], pxl[2];
    if (xi & 1) { ntx = 2; txl[0] = 0; pxl[0] = (xi + 1) >> 1; txl[1] = 2; pxl[1] = (xi - 1) >> 1; }
    else        { ntx = 1; txl[0] = 1; pxl[0] = xi >> 1; txl[1] = 1; pxl[1] = xi >> 1; }
    int oy0 = 2 * q;
    #pragma unroll
    for (int ck = 0; ck < 4; ++ck) {
        int c = cq + ck * 16;
        float v0 = 0.f, v1 = 0.f;
        for (int j = 0; j < ntx; ++j) {
            int tx = txl[j], pxi = pxl[j];
            v0 += zb[(0 * 9 + pxi) * 580 + (3 + tx) * 64 + c];
            v1 += zb[(1 * 9 + pxi) * 580 + (0 + tx) * 64 + c];
            v1 += zb[(0 * 9 + pxi) * 580 + (6 + tx) * 64 + c];
        }
        if (oxv) {
            float* o = out + (((size_t)(b * 64 + c) * 191 + oy0) * 191 + ox);
            *o = v0;
            if (q < 95) *(o + 191) = v1;
        }
    }
}

// --------------------------------------------------------------------- host
extern "C" void kernel_launch(void* const* d_in, const int* in_sizes, int n_in,
                              void* d_out, int out_size, void* d_ws, size_t ws_size,
                              hipStream_t stream) {
    const float* input = (const float*)d_in[0];
    const float* small = (const float*)d_in[1];
    const float* w1 = (const float*)d_in[2];
    const float* b1 = (const float*)d_in[3];
    const float* a1 = (const float*)d_in[4];
    const float* w2 = (const float*)d_in[5];
    const float* b2 = (const float*)d_in[6];
    const float* a2 = (const float*)d_in[7];
    const float* wa = (const float*)d_in[8];
    const float* ba = (const float*)d_in[9];
    const float* aa = (const float*)d_in[10];

    char* ws = (char*)d_ws;
    u16* xf16 = (u16*)(ws + 0);             //  2,458,624
    u16* rkl = (u16*)(ws + 2458624);        //    640,000
    float* ef = (float*)(ws + 3098624);     //  2,560,000
    u16* vtp = (u16*)(ws + 5658624);        // 10,616,832
    float* invn = (float*)(ws + 16275456);  //     36,864
    const size_t PREP = 16312320;
    float* Zbuf = (float*)(ws + PREP);      // nb*21,233,664
    float* out = (float*)d_out;

    int nb = (ws_size >= (size_t)101246976) ? 4 : 1;

    kzero<<<1024, 256, 0, stream>>>((float4*)ws, 5658624 / 16);   // halo'd arrays
    kmatch<<<384, 256, 0, stream>>>(input, w1, b1, a1, xf16);
    ksmall<<<192, 256, 0, stream>>>(small, wa, ba, aa, w2, b2, a2, ef, rkl);
    kinvnorm<<<36, 256, 0, stream>>>(rkl, invn);
    kvtp<<<192, 256, 0, stream>>>(ef, vtp);

    for (int b0 = 0; b0 < 4; b0 += nb) {
        kfused3<<<nb * 144, 256, 0, stream>>>(xf16, rkl, vtp, invn, Zbuf, b0, nb);
        kgather<<<nb * 1152, 256, 0, stream>>>(Zbuf, out, b0);
    }
}

// Round 7
// 533.395 us; speedup vs baseline: 1.1964x; 1.1049x over previous
//
#include <hip/hip_runtime.h>

// CrossScaleAttention on MI355X — round 12.
// R11 post-mortem: row-major score SPILLED (sf0+sf1 doubled live score
// state; FETCH 12.5->30MB, WRITE 103->137MB, 358->422us) -> pre-committed
// revert of (a). kvtp rewrite GOOD (rest 182->167us) -> keep.
// R12 = assembly of proven parts only:
//   kfused3 = exact R9 (358us), kvtp = R11 coalesced, kgather = R8 2-row
//   (3 staged rows, -25% Z reads, half the blocks; correctness proven in
//   R8's passing run, perf previously confounded by R8's spill).
// Pre-committed: kfused ~358 / FETCH ~12.5MB / kgather ~90-100 =>
// total ~495-515. kgather flat => Z-traffic model wrong, revert it.
//
// Workspace (101,246,976 B; known-good >= 105.6 MB):
//   xf16 : [4][98][98][32] fp16 match_input, zero halo        2,458,624
//   rkl  : [4][50][50][32] fp16 ref, zero halo                  640,000
//   ef32 : [4][50][50][64] f32 embed_w, zero halo             2,560,000
//   vtp  : [4][576][2304] bf16 V^T (n=tap*64+c, l=ly*48+lx)  10,616,832
//   invn : [4][2304] f32 10/max(norm,1e-4)                       36,864
//   Z    : [nb][9216][576] f32                            nb*21,233,664

typedef unsigned short u16;
typedef __attribute__((ext_vector_type(8))) short short8;      // 8 bf16
typedef __attribute__((ext_vector_type(8))) _Float16 half8;    // 8 fp16
typedef __attribute__((ext_vector_type(4))) float f32x4;

__device__ __forceinline__ u16 f2bf(float f) {
    unsigned u = __float_as_uint(f);
    unsigned r = (u + 0x7FFFu + ((u >> 16) & 1u)) >> 16;   // RNE
    return (u16)r;
}
__device__ __forceinline__ float bf2f(u16 h) {
    return __uint_as_float(((unsigned)h) << 16);
}
__device__ __forceinline__ u16 f2h(float f) {
    _Float16 h = (_Float16)f;           // v_cvt_f16_f32 (RNE)
    u16 u; __builtin_memcpy(&u, &h, 2); return u;
}
__device__ __forceinline__ float h2f(u16 u) {
    _Float16 h; __builtin_memcpy(&h, &u, 2); return (float)h;
}

// ---------------------------------------------------------------- zero fill
__global__ void kzero(float4* p, long n) {
    long i = (long)blockIdx.x * blockDim.x + threadIdx.x;
    long st = (long)gridDim.x * blockDim.x;
    float4 z; z.x = 0.f; z.y = 0.f; z.z = 0.f; z.w = 0.f;
    for (; i < n; i += st) p[i] = z;
}

// ------------------------------------------------- match_input -> xf16
__global__ void kmatch(const float* __restrict__ input, const float* __restrict__ w1,
                       const float* __restrict__ b1, const float* __restrict__ a1,
                       u16* __restrict__ xf16) {
    __shared__ float xl[64 * 96];
    __shared__ float wl[32 * 65];
    int b = blockIdx.x / 96, y = blockIdx.x % 96;
    int tid = threadIdx.x;
    for (int i = tid; i < 64 * 96; i += 256) {
        int ci = i / 96, xx = i % 96;
        xl[i] = input[(((b * 64 + ci) * 96) + y) * 96 + xx];
    }
    for (int i = tid; i < 2048; i += 256) wl[(i >> 6) * 65 + (i & 63)] = w1[i];
    __syncthreads();
    float aa = a1[0];
    for (int o = tid; o < 96 * 32; o += 256) {
        int xx = o >> 5, c = o & 31;
        float acc = b1[c];
        #pragma unroll
        for (int ci = 0; ci < 64; ci++) acc = fmaf(xl[ci * 96 + xx], wl[c * 65 + ci], acc);
        float v = acc >= 0.f ? acc : aa * acc;
        xf16[((b * 98 + y + 1) * 98 + (xx + 1)) * 32 + c] = f2h(v);
    }
}

// --------------------- small -> ef32 (embed, f32) + rkl fp16 (ref)
__global__ void ksmall(const float* __restrict__ small, const float* __restrict__ wasm,
                       const float* __restrict__ basm, const float* __restrict__ aasm,
                       const float* __restrict__ wm2, const float* __restrict__ bm2,
                       const float* __restrict__ am2,
                       float* __restrict__ ef32, u16* __restrict__ rkl) {
    __shared__ float sl[64 * 48];
    __shared__ float wa[64 * 65];
    __shared__ float wm[32 * 65];
    int b = blockIdx.x / 48, y = blockIdx.x % 48;
    int tid = threadIdx.x;
    for (int i = tid; i < 64 * 48; i += 256) {
        int ci = i / 48, xx = i % 48;
        sl[i] = small[(((b * 64 + ci) * 48) + y) * 48 + xx];
    }
    for (int i = tid; i < 4096; i += 256) wa[(i >> 6) * 65 + (i & 63)] = wasm[i];
    for (int i = tid; i < 2048; i += 256) wm[(i >> 6) * 65 + (i & 63)] = wm2[i];
    __syncthreads();
    float ae = aasm[0], ar = am2[0];
    for (int o = tid; o < 48 * 64; o += 256) {            // embed_w
        int xx = o >> 6, c = o & 63;
        float acc = basm[c];
        #pragma unroll
        for (int ci = 0; ci < 64; ci++) acc = fmaf(sl[ci * 48 + xx], wa[c * 65 + ci], acc);
        float v = acc >= 0.f ? acc : ae * acc;
        ef32[((b * 50 + y + 1) * 50 + (xx + 1)) * 64 + c] = v;
    }
    for (int o = tid; o < 48 * 32; o += 256) {            // ref -> rkl fp16
        int xx = o >> 5, c = o & 31;
        float acc = bm2[c];
        #pragma unroll
        for (int ci = 0; ci < 64; ci++) acc = fmaf(sl[ci * 48 + xx], wm[c * 65 + ci], acc);
        float v = acc >= 0.f ? acc : ar * acc;
        rkl[((b * 50 + y + 1) * 50 + (xx + 1)) * 32 + c] = f2h(v);
    }
}

// ------------------------------------------------------------ invnorm per key
__global__ void kinvnorm(const u16* __restrict__ rkl, float* __restrict__ invn) {
    int idx = blockIdx.x * 256 + threadIdx.x;   // 9216 exact
    int b = idx / 2304, l = idx % 2304;
    int ly = l / 48, lx = l % 48;
    float s = 0.f;
    for (int ty = 0; ty < 3; ty++)
        for (int tx = 0; tx < 3; tx++) {
            int base = ((b * 50 + ly + ty) * 50 + (lx + tx)) * 32;
            #pragma unroll
            for (int c = 0; c < 32; c++) {
                float v = h2f(rkl[base + c]);
                s = fmaf(v, v, s);
            }
        }
    invn[idx] = 10.f / fmaxf(sqrtf(s), 1e-4f);   // SCALE folded in
}

// ------------------------------------------------------------- pack V^T bf16
// Block per (b, ly). Stage ef rows ly..ly+2 in LDS (coalesced reads),
// write each n-row's 48-element segment contiguously (coalesced 8B stores).
__global__ void kvtp(const float* __restrict__ ef32, u16* __restrict__ vtp) {
    __shared__ float el[3][50 * 64];    // 38400 B
    int bi = blockIdx.x;                // 4*48
    int b = bi / 48, ly = bi % 48;
    const float* eb = ef32 + (size_t)b * 50 * 50 * 64;
    int tid = threadIdx.x;
    #pragma unroll
    for (int r = 0; r < 3; ++r)
        for (int i = tid; i < 800; i += 256)
            ((float4*)el[r])[i] = ((const float4*)(eb + (size_t)(ly + r) * 3200))[i];
    __syncthreads();
    u16* vo = vtp + (size_t)b * 576 * 2304 + (size_t)ly * 48;
    for (int n = tid; n < 576; n += 256) {
        int t = n >> 6, c = n & 63;
        int ty = t / 3, tx = t - ty * 3;
        u16* dst = vo + (size_t)n * 2304;
        const float* src = &el[ty][tx * 64 + c];
        #pragma unroll
        for (int g = 0; g < 12; ++g) {
            unsigned lo = (unsigned)f2bf(src[(g * 4 + 0) * 64]) |
                          ((unsigned)f2bf(src[(g * 4 + 1) * 64]) << 16);
            unsigned hi = (unsigned)f2bf(src[(g * 4 + 2) * 64]) |
                          ((unsigned)f2bf(src[(g * 4 + 3) * 64]) << 16);
            uint2 pk; pk.x = lo; pk.y = hi;
            *(uint2*)&dst[g * 4] = pk;   // 8B aligned: 2304*2B row stride, 96B base
        }
    }
}

// ---------------------------------------------- async Ks staging (12800 B)
__device__ __forceinline__ void stage_ks(const u16* __restrict__ src, u16* dst, int tid) {
    int wb = tid & ~63;   // wave-uniform LDS base
    #pragma unroll
    for (int k = 0; k < 3; ++k)
        __builtin_amdgcn_global_load_lds(
            (const __attribute__((address_space(1))) void*)(src + (size_t)(tid + k * 256) * 8),
            (__attribute__((address_space(3))) void*)(dst + (size_t)(wb + k * 256) * 8),
            16, 0, 0);
    if (tid < 32)   // tail: 800*16B total, lanes 0..31 of wave 0
        __builtin_amdgcn_global_load_lds(
            (const __attribute__((address_space(1))) void*)(src + (size_t)(tid + 768) * 8),
            (__attribute__((address_space(3))) void*)(dst + (size_t)768 * 8),
            16, 0, 0);
}

// ------------------------------------------------------------- fused score+PV
// EXACT R9 (358us): grid = nb*144; block = 256 (4 waves). BM=64 queries
// (4 py-rows x 16 px), BN=96 keys/iter, 24 iters. Wave w: score for q-tile
// w (both key halves), PV for n-quarter w over all 64 q (acc[4][9]).
// Q tile in LDS. One counted-vmcnt barrier per iter (vmcnt(9)).
__launch_bounds__(256, 2)
__global__ void kfused3(const u16* __restrict__ xf16, const u16* __restrict__ rkl,
                        const u16* __restrict__ vtp, const float* __restrict__ invn,
                        float* __restrict__ Z, int b0, int nb) {
    __shared__ u16 Ks[2][6400];     // 25600 B: dbuf, 4 halo rows x [50 px][32 c] fp16
    __shared__ u16 Pl[2][6144];     // 24576 B: dbuf, [4 mtile][3 kb][16 m][32 kc]
    __shared__ float Ln[2304];      //  9216 B: invn for this batch
    __shared__ u16 Qs[6 * 18 * 32]; //  6912 B: Q tile rows pyb..pyb+5, px0..px0+17
    __shared__ float llds[4][16];   //   256 B  -> 66560 B total

    int tid = threadIdx.x;
    int w = tid >> 6, lane = tid & 63, l15 = lane & 15, quad = lane >> 4;
    int bi = blockIdx.x, brel, t;
    if (nb == 4) { brel = bi & 3; t = bi >> 2; }
    else         { brel = 0; t = bi; }
    int b = b0 + brel;
    int px0 = (t % 6) * 16, pyb = (t / 6) * 4;     // 6 x-tiles x 24 y-groups = 144

    const u16* xb = xf16 + (size_t)b * 98 * 98 * 32;
    const u16* rb = rkl + (size_t)b * 50 * 50 * 32;
    const float* invb = invn + b * 2304;
    const u16* vw = vtp + (size_t)b * 576 * 2304 + (size_t)(w * 144 + l15) * 2304 + quad * 8;

    stage_ks(rb, Ks[0], tid);       // async; drained by the prologue barrier
    __builtin_amdgcn_sched_barrier(0);

    // invn -> LDS (once)
    for (int i = tid; i < 576; i += 256)
        ((float4*)Ln)[i] = ((const float4*)invb)[i];

    // Q tile -> LDS (once): 6 rows x 18 px x 32 c fp16 = 108 cells x 4 chunks
    for (int u = tid; u < 432; u += 256) {
        int cell = u >> 2, ch = u & 3;
        int r = cell / 18, p = cell % 18;
        *(short8*)&Qs[(r * 18 + p) * 32 + ch * 8] =
            *(const short8*)(xb + (((pyb + r) * 98) + (px0 + p)) * 32 + ch * 8);
    }

    f32x4 acc[36];
    #pragma unroll
    for (int i = 0; i < 36; i++) acc[i] = (f32x4)0.f;
    float lacc[4] = {0.f, 0.f, 0.f, 0.f};

    __syncthreads();   // prologue: full drain (Ks[0] DMA + Ln + Qs staged)

    short8 vv[9];

    for (int it = 0; it < 24; ++it) {
        int ly0 = it * 2;
        int cur = it & 1;

        // ---- 1. DMA next Ks (oldest VMEM of this iter — vmcnt(9) relies on it)
        if (it < 23) stage_ks(rb + (ly0 + 2) * 1600, Ks[cur ^ 1], tid);
        __builtin_amdgcn_sched_barrier(0);   // pin DMA-first issue order

        // ---- 2. V ks=0 loads (9; ride across the barrier into PV)
        const u16* vit = vw + it * 96;
        #pragma unroll
        for (int nt = 0; nt < 9; ++nt) vv[nt] = *(const short8*)(vit + (size_t)nt * 36864);

        // ---- 3+4. score + exp for both key halves of this wave's q-tile
        const u16* Kc = Ks[cur];
        u16* Pc = Pl[cur];
        #pragma unroll
        for (int kh = 0; kh < 2; ++kh) {
            f32x4 sf[3];
            #pragma unroll
            for (int i = 0; i < 3; i++) sf[i] = (f32x4)0.f;
            __builtin_amdgcn_s_setprio(1);
            #pragma unroll
            for (int ty = 0; ty < 3; ++ty)
                #pragma unroll
                for (int tx = 0; tx < 3; ++tx) {
                    half8 a = *(const half8*)&Qs[((w + ty) * 18 + (l15 + tx)) * 32 + quad * 8];
                    #pragma unroll
                    for (int lxo = 0; lxo < 3; ++lxo) {
                        half8 bb = *(const half8*)&Kc[(kh + ty) * 1600 + (lxo * 16 + l15 + tx) * 32 + quad * 8];
                        sf[lxo] = __builtin_amdgcn_mfma_f32_16x16x32_f16(a, bb, sf[lxo], 0, 0, 0);
                    }
                }
            __builtin_amdgcn_s_setprio(0);
            #pragma unroll
            for (int lxo = 0; lxo < 3; ++lxo) {
                float invs = Ln[(ly0 + kh) * 48 + lxo * 16 + l15];
                int k = kh * 48 + lxo * 16 + l15;
                int kb = k >> 5;
                int kc = (k & 31) ^ (quad << 3);   // XOR swizzle by quad (= m>>2)
                #pragma unroll
                for (int r = 0; r < 4; ++r) {
                    float p = __expf(sf[lxo][r] * invs);
                    u16 h = f2bf(p);
                    Pc[(w * 3 + kb) * 512 + (quad * 4 + r) * 32 + kc] = h;
                    lacc[r] += bf2f(h);   // l exactly as the PV MFMA sees P
                }
            }
        }

        // ---- 5. counted-vmcnt barrier: Pl visible (lgkm 0) + Ks DMA landed
        // (vmcnt<=9: the 9 newer vv loads may stay in flight).
        asm volatile("s_waitcnt vmcnt(9) lgkmcnt(0)" ::: "memory");
        __builtin_amdgcn_s_barrier();
        __builtin_amdgcn_sched_barrier(0);

        // ---- 6. PV: O[64, this wave's 144 cols] += P[64,96] @ V[96,144], bf16
        const u16* Pr = Pl[cur];
        int pcol = l15 * 32 + ((quad ^ (l15 >> 2)) & 3) * 8;
        __builtin_amdgcn_s_setprio(1);
        #pragma unroll
        for (int ks = 0; ks < 3; ++ks) {
            short8 pa0 = *(const short8*)&Pr[(0 * 3 + ks) * 512 + pcol];
            short8 pa1 = *(const short8*)&Pr[(1 * 3 + ks) * 512 + pcol];
            #pragma unroll
            for (int nt = 0; nt < 9; ++nt) {
                short8 vn = vv[nt];
                acc[0 * 9 + nt] = __builtin_amdgcn_mfma_f32_16x16x32_bf16(pa0, vn, acc[0 * 9 + nt], 0, 0, 0);
                acc[1 * 9 + nt] = __builtin_amdgcn_mfma_f32_16x16x32_bf16(pa1, vn, acc[1 * 9 + nt], 0, 0, 0);
            }
            pa0 = *(const short8*)&Pr[(2 * 3 + ks) * 512 + pcol];
            pa1 = *(const short8*)&Pr[(3 * 3 + ks) * 512 + pcol];
            #pragma unroll
            for (int nt = 0; nt < 9; ++nt) {
                short8 vn = vv[nt];
                acc[2 * 9 + nt] = __builtin_amdgcn_mfma_f32_16x16x32_bf16(pa0, vn, acc[2 * 9 + nt], 0, 0, 0);
                acc[3 * 9 + nt] = __builtin_amdgcn_mfma_f32_16x16x32_bf16(pa1, vn, acc[3 * 9 + nt], 0, 0, 0);
                if (ks < 2)   // reload right after last use; covered by rest of phase
                    vv[nt] = *(const short8*)(vit + (size_t)nt * 36864 + (ks + 1) * 32);
            }
        }
        __builtin_amdgcn_s_setprio(0);
    }

    // ---- epilogue: reduce l over l15; share per-tile l via LDS; Z = O/(6l)
    #pragma unroll
    for (int r = 0; r < 4; ++r) {
        float v = lacc[r];
        v += __shfl_xor(v, 1);
        v += __shfl_xor(v, 2);
        v += __shfl_xor(v, 4);
        v += __shfl_xor(v, 8);
        lacc[r] = v;
    }
    if (l15 == 0) {
        #pragma unroll
        for (int r = 0; r < 4; ++r)
            llds[w][quad * 4 + r] = lacc[r];
    }
    __syncthreads();
    float* Zb = Z + (size_t)brel * 9216 * 576;
    #pragma unroll
    for (int mt = 0; mt < 4; ++mt) {
        #pragma unroll
        for (int r = 0; r < 4; ++r) {
            int q = (pyb + mt) * 96 + px0 + quad * 4 + r;
            float rl = 1.0f / (llds[mt][quad * 4 + r] * 6.0f);
            float* zr = Zb + (size_t)q * 576 + w * 144;
            #pragma unroll
            for (int nt = 0; nt < 9; ++nt)
                __builtin_nontemporal_store(acc[mt * 9 + nt][r] * rl, zr + nt * 16 + l15);
        }
    }
}

// ------------------------------------------------------------- gather (Z -> out)
// 2 q-rows per block: stage 3 py rows (vs 2x2), -25% Z reads, half the blocks.
__global__ void kgather(const float* __restrict__ Z, float* __restrict__ out, int b0) {
    __shared__ float zb[3 * 9 * 580];   // 62640 B
    int bi = blockIdx.x;                // nb*48*12
    int brel = bi / (48 * 12);
    int rem = bi % (48 * 12);
    int b = b0 + brel;
    int j = rem / 12, xt = rem % 12;
    int q0 = 2 * j;
    int ox0 = xt * 16, p0 = ox0 >> 1;
    const float* Zb = Z + (size_t)brel * 9216 * 576;
    int tid = threadIdx.x;
    for (int id = tid; id < 3888; id += 256) {
        int pi = id / 1296, r2 = id % 1296;
        int pxi = r2 / 144, n4 = r2 % 144;
        int py = q0 + pi; if (py > 95) py = 95;
        int px = p0 + pxi; if (px > 95) px = 95;
        *(float4*)&zb[(pi * 9 + pxi) * 580 + n4 * 4] =
            *(const float4*)&Zb[(size_t)(py * 96 + px) * 576 + n4 * 4];
    }
    __syncthreads();
    int xi = tid & 15, cq = tid >> 4;
    int ox = ox0 + xi;
    bool oxv = ox <= 190;
    int ntx, txl[2], pxl[2];
    if (xi & 1) { ntx = 2; txl[0] = 0; pxl[0] = (xi + 1) >> 1; txl[1] = 2; pxl[1] = (xi - 1) >> 1; }
    else        { ntx = 1; txl[0] = 1; pxl[0] = xi >> 1; txl[1] = 1; pxl[1] = xi >> 1; }
    #pragma unroll
    for (int sq = 0; sq < 2; ++sq) {
        int q = q0 + sq;
        int oy0 = 2 * q;
        #pragma unroll
        for (int ck = 0; ck < 4; ++ck) {
            int c = cq + ck * 16;
            float v0 = 0.f, v1 = 0.f;
            for (int jj = 0; jj < ntx; ++jj) {
                int tx = txl[jj], pxi = pxl[jj];
                v0 += zb[((sq + 0) * 9 + pxi) * 580 + (3 + tx) * 64 + c];
                v1 += zb[((sq + 1) * 9 + pxi) * 580 + (0 + tx) * 64 + c];
                v1 += zb[((sq + 0) * 9 + pxi) * 580 + (6 + tx) * 64 + c];
            }
            if (oxv) {
                float* o = out + (((size_t)(b * 64 + c) * 191 + oy0) * 191 + ox);
                *o = v0;
                if (q < 95) *(o + 191) = v1;
            }
        }
    }
}

// --------------------------------------------------------------------- host
extern "C" void kernel_launch(void* const* d_in, const int* in_sizes, int n_in,
                              void* d_out, int out_size, void* d_ws, size_t ws_size,
                              hipStream_t stream) {
    const float* input = (const float*)d_in[0];
    const float* small = (const float*)d_in[1];
    const float* w1 = (const float*)d_in[2];
    const float* b1 = (const float*)d_in[3];
    const float* a1 = (const float*)d_in[4];
    const float* w2 = (const float*)d_in[5];
    const float* b2 = (const float*)d_in[6];
    const float* a2 = (const float*)d_in[7];
    const float* wa = (const float*)d_in[8];
    const float* ba = (const float*)d_in[9];
    const float* aa = (const float*)d_in[10];

    char* ws = (char*)d_ws;
    u16* xf16 = (u16*)(ws + 0);             //  2,458,624
    u16* rkl = (u16*)(ws + 2458624);        //    640,000
    float* ef = (float*)(ws + 3098624);     //  2,560,000
    u16* vtp = (u16*)(ws + 5658624);        // 10,616,832
    float* invn = (float*)(ws + 16275456);  //     36,864
    const size_t PREP = 16312320;
    float* Zbuf = (float*)(ws + PREP);      // nb*21,233,664
    float* out = (float*)d_out;

    int nb = (ws_size >= (size_t)101246976) ? 4 : 1;

    kzero<<<1024, 256, 0, stream>>>((float4*)ws, 5658624 / 16);   // halo'd arrays
    kmatch<<<384, 256, 0, stream>>>(input, w1, b1, a1, xf16);
    ksmall<<<192, 256, 0, stream>>>(small, wa, ba, aa, w2, b2, a2, ef, rkl);
    kinvnorm<<<36, 256, 0, stream>>>(rkl, invn);
    kvtp<<<192, 256, 0, stream>>>(ef, vtp);

    for (int b0 = 0; b0 < 4; b0 += nb) {
        kfused3<<<nb * 144, 256, 0, stream>>>(xf16, rkl, vtp, invn, Zbuf, b0, nb);
        kgather<<<nb * 576, 256, 0, stream>>>(Zbuf, out, b0);
    }
}

// Round 9
// 528.751 us; speedup vs baseline: 1.2069x; 1.0088x over previous
//
#include <hip/hip_runtime.h>

// CrossScaleAttention on MI355X — round 14 (= R13 resubmit; bench infra
// failed twice, no data — hypothesis untested).
// R12 post-mortem: kfused3 ~362 clean (R9 baseline restored); kgather 2-row
// flat-to-neg (rest 171 vs 167) -> reverted to R7 1-row per pre-commit.
// Slot budget: LDS ~42%, MFMA ~14%, VALU ~10% -> ~30% pure bubble. Pl and
// Ks are BOTH double-buffered (no barrier between PV(it) and score(it+1)),
// but the sched_barrier(0) after the DMA issue walls off DS/MFMA/VALU too,
// serializing PV's MFMA-dense stream against score's LDS-dense stream.
// R13/R14: relax that wall to sched_barrier(0x38F) = allow ALU|VALU|SALU|
// MFMA|DS|DS_READ|DS_WRITE to cross, keep VMEM (0x10|0x20|0x40) pinned ->
// the DMA-oldest/vmcnt(9) invariant is untouched; compiler may interleave
// score(it+1) ds_reads/MFMAs into PV(it). Safety: P(it+1) writes hit
// Pl[cur^1] (disjoint from PV's Pl[cur]); lacc is a sequential dep chain
// (bit-identical). Post-s_barrier wall stays mask 0.
// Pre-committed: kfused ~310-335 => interleave confirmed; FETCH >15MB =>
// over-hoist spill, revert mask; neutral + MfmaUtil flat => compiler
// declined, do manual code motion next round.
//
// Workspace (101,246,976 B; known-good >= 105.6 MB):
//   xf16 : [4][98][98][32] fp16 match_input, zero halo        2,458,624
//   rkl  : [4][50][50][32] fp16 ref, zero halo                  640,000
//   ef32 : [4][50][50][64] f32 embed_w, zero halo             2,560,000
//   vtp  : [4][576][2304] bf16 V^T (n=tap*64+c, l=ly*48+lx)  10,616,832
//   invn : [4][2304] f32 10/max(norm,1e-4)                       36,864
//   Z    : [nb][9216][576] f32                            nb*21,233,664

typedef unsigned short u16;
typedef __attribute__((ext_vector_type(8))) short short8;      // 8 bf16
typedef __attribute__((ext_vector_type(8))) _Float16 half8;    // 8 fp16
typedef __attribute__((ext_vector_type(4))) float f32x4;

__device__ __forceinline__ u16 f2bf(float f) {
    unsigned u = __float_as_uint(f);
    unsigned r = (u + 0x7FFFu + ((u >> 16) & 1u)) >> 16;   // RNE
    return (u16)r;
}
__device__ __forceinline__ float bf2f(u16 h) {
    return __uint_as_float(((unsigned)h) << 16);
}
__device__ __forceinline__ u16 f2h(float f) {
    _Float16 h = (_Float16)f;           // v_cvt_f16_f32 (RNE)
    u16 u; __builtin_memcpy(&u, &h, 2); return u;
}
__device__ __forceinline__ float h2f(u16 u) {
    _Float16 h; __builtin_memcpy(&h, &u, 2); return (float)h;
}

// ---------------------------------------------------------------- zero fill
__global__ void kzero(float4* p, long n) {
    long i = (long)blockIdx.x * blockDim.x + threadIdx.x;
    long st = (long)gridDim.x * blockDim.x;
    float4 z; z.x = 0.f; z.y = 0.f; z.z = 0.f; z.w = 0.f;
    for (; i < n; i += st) p[i] = z;
}

// ------------------------------------------------- match_input -> xf16
__global__ void kmatch(const float* __restrict__ input, const float* __restrict__ w1,
                       const float* __restrict__ b1, const float* __restrict__ a1,
                       u16* __restrict__ xf16) {
    __shared__ float xl[64 * 96];
    __shared__ float wl[32 * 65];
    int b = blockIdx.x / 96, y = blockIdx.x % 96;
    int tid = threadIdx.x;
    for (int i = tid; i < 64 * 96; i += 256) {
        int ci = i / 96, xx = i % 96;
        xl[i] = input[(((b * 64 + ci) * 96) + y) * 96 + xx];
    }
    for (int i = tid; i < 2048; i += 256) wl[(i >> 6) * 65 + (i & 63)] = w1[i];
    __syncthreads();
    float aa = a1[0];
    for (int o = tid; o < 96 * 32; o += 256) {
        int xx = o >> 5, c = o & 31;
        float acc = b1[c];
        #pragma unroll
        for (int ci = 0; ci < 64; ci++) acc = fmaf(xl[ci * 96 + xx], wl[c * 65 + ci], acc);
        float v = acc >= 0.f ? acc : aa * acc;
        xf16[((b * 98 + y + 1) * 98 + (xx + 1)) * 32 + c] = f2h(v);
    }
}

// --------------------- small -> ef32 (embed, f32) + rkl fp16 (ref)
__global__ void ksmall(const float* __restrict__ small, const float* __restrict__ wasm,
                       const float* __restrict__ basm, const float* __restrict__ aasm,
                       const float* __restrict__ wm2, const float* __restrict__ bm2,
                       const float* __restrict__ am2,
                       float* __restrict__ ef32, u16* __restrict__ rkl) {
    __shared__ float sl[64 * 48];
    __shared__ float wa[64 * 65];
    __shared__ float wm[32 * 65];
    int b = blockIdx.x / 48, y = blockIdx.x % 48;
    int tid = threadIdx.x;
    for (int i = tid; i < 64 * 48; i += 256) {
        int ci = i / 48, xx = i % 48;
        sl[i] = small[(((b * 64 + ci) * 48) + y) * 48 + xx];
    }
    for (int i = tid; i < 4096; i += 256) wa[(i >> 6) * 65 + (i & 63)] = wasm[i];
    for (int i = tid; i < 2048; i += 256) wm[(i >> 6) * 65 + (i & 63)] = wm2[i];
    __syncthreads();
    float ae = aasm[0], ar = am2[0];
    for (int o = tid; o < 48 * 64; o += 256) {            // embed_w
        int xx = o >> 6, c = o & 63;
        float acc = basm[c];
        #pragma unroll
        for (int ci = 0; ci < 64; ci++) acc = fmaf(sl[ci * 48 + xx], wa[c * 65 + ci], acc);
        float v = acc >= 0.f ? acc : ae * acc;
        ef32[((b * 50 + y + 1) * 50 + (xx + 1)) * 64 + c] = v;
    }
    for (int o = tid; o < 48 * 32; o += 256) {            // ref -> rkl fp16
        int xx = o >> 5, c = o & 31;
        float acc = bm2[c];
        #pragma unroll
        for (int ci = 0; ci < 64; ci++) acc = fmaf(sl[ci * 48 + xx], wm[c * 65 + ci], acc);
        float v = acc >= 0.f ? acc : ar * acc;
        rkl[((b * 50 + y + 1) * 50 + (xx + 1)) * 32 + c] = f2h(v);
    }
}

// ------------------------------------------------------------ invnorm per key
__global__ void kinvnorm(const u16* __restrict__ rkl, float* __restrict__ invn) {
    int idx = blockIdx.x * 256 + threadIdx.x;   // 9216 exact
    int b = idx / 2304, l = idx % 2304;
    int ly = l / 48, lx = l % 48;
    float s = 0.f;
    for (int ty = 0; ty < 3; ty++)
        for (int tx = 0; tx < 3; tx++) {
            int base = ((b * 50 + ly + ty) * 50 + (lx + tx)) * 32;
            #pragma unroll
            for (int c = 0; c < 32; c++) {
                float v = h2f(rkl[base + c]);
                s = fmaf(v, v, s);
            }
        }
    invn[idx] = 10.f / fmaxf(sqrtf(s), 1e-4f);   // SCALE folded in
}

// ------------------------------------------------------------- pack V^T bf16
// Block per (b, ly). Stage ef rows ly..ly+2 in LDS (coalesced reads),
// write each n-row's 48-element segment contiguously (coalesced 8B stores).
__global__ void kvtp(const float* __restrict__ ef32, u16* __restrict__ vtp) {
    __shared__ float el[3][50 * 64];    // 38400 B
    int bi = blockIdx.x;                // 4*48
    int b = bi / 48, ly = bi % 48;
    const float* eb = ef32 + (size_t)b * 50 * 50 * 64;
    int tid = threadIdx.x;
    #pragma unroll
    for (int r = 0; r < 3; ++r)
        for (int i = tid; i < 800; i += 256)
            ((float4*)el[r])[i] = ((const float4*)(eb + (size_t)(ly + r) * 3200))[i];
    __syncthreads();
    u16* vo = vtp + (size_t)b * 576 * 2304 + (size_t)ly * 48;
    for (int n = tid; n < 576; n += 256) {
        int t = n >> 6, c = n & 63;
        int ty = t / 3, tx = t - ty * 3;
        u16* dst = vo + (size_t)n * 2304;
        const float* src = &el[ty][tx * 64 + c];
        #pragma unroll
        for (int g = 0; g < 12; ++g) {
            unsigned lo = (unsigned)f2bf(src[(g * 4 + 0) * 64]) |
                          ((unsigned)f2bf(src[(g * 4 + 1) * 64]) << 16);
            unsigned hi = (unsigned)f2bf(src[(g * 4 + 2) * 64]) |
                          ((unsigned)f2bf(src[(g * 4 + 3) * 64]) << 16);
            uint2 pk; pk.x = lo; pk.y = hi;
            *(uint2*)&dst[g * 4] = pk;   // 8B aligned: 2304*2B row stride, 96B base
        }
    }
}

// ---------------------------------------------- async Ks staging (12800 B)
__device__ __forceinline__ void stage_ks(const u16* __restrict__ src, u16* dst, int tid) {
    int wb = tid & ~63;   // wave-uniform LDS base
    #pragma unroll
    for (int k = 0; k < 3; ++k)
        __builtin_amdgcn_global_load_lds(
            (const __attribute__((address_space(1))) void*)(src + (size_t)(tid + k * 256) * 8),
            (__attribute__((address_space(3))) void*)(dst + (size_t)(wb + k * 256) * 8),
            16, 0, 0);
    if (tid < 32)   // tail: 800*16B total, lanes 0..31 of wave 0
        __builtin_amdgcn_global_load_lds(
            (const __attribute__((address_space(1))) void*)(src + (size_t)(tid + 768) * 8),
            (__attribute__((address_space(3))) void*)(dst + (size_t)768 * 8),
            16, 0, 0);
}

// ------------------------------------------------------------- fused score+PV
// grid = nb*144; block = 256 (4 waves). BM=64 queries (4 py-rows x 16 px),
// BN=96 keys/iter, 24 iters. Wave w: score for q-tile w (both key halves),
// PV for n-quarter w over all 64 q (acc[4][9]). Q tile in LDS. One counted
// vmcnt barrier per iter. R14: the post-DMA scheduling wall allows compute
// and DS to cross (mask 0x38F) so PV(it) and score(it+1) interleave; VMEM
// order stays pinned (vmcnt(9) invariant intact).
__launch_bounds__(256, 2)
__global__ void kfused3(const u16* __restrict__ xf16, const u16* __restrict__ rkl,
                        const u16* __restrict__ vtp, const float* __restrict__ invn,
                        float* __restrict__ Z, int b0, int nb) {
    __shared__ u16 Ks[2][6400];     // 25600 B: dbuf, 4 halo rows x [50 px][32 c] fp16
    __shared__ u16 Pl[2][6144];     // 24576 B: dbuf, [4 mtile][3 kb][16 m][32 kc]
    __shared__ float Ln[2304];      //  9216 B: invn for this batch
    __shared__ u16 Qs[6 * 18 * 32]; //  6912 B: Q tile rows pyb..pyb+5, px0..px0+17
    __shared__ float llds[4][16];   //   256 B  -> 66560 B total

    int tid = threadIdx.x;
    int w = tid >> 6, lane = tid & 63, l15 = lane & 15, quad = lane >> 4;
    int bi = blockIdx.x, brel, t;
    if (nb == 4) { brel = bi & 3; t = bi >> 2; }
    else         { brel = 0; t = bi; }
    int b = b0 + brel;
    int px0 = (t % 6) * 16, pyb = (t / 6) * 4;     // 6 x-tiles x 24 y-groups = 144

    const u16* xb = xf16 + (size_t)b * 98 * 98 * 32;
    const u16* rb = rkl + (size_t)b * 50 * 50 * 32;
    const float* invb = invn + b * 2304;
    const u16* vw = vtp + (size_t)b * 576 * 2304 + (size_t)(w * 144 + l15) * 2304 + quad * 8;

    stage_ks(rb, Ks[0], tid);       // async; drained by the prologue barrier
    __builtin_amdgcn_sched_barrier(0);

    // invn -> LDS (once)
    for (int i = tid; i < 576; i += 256)
        ((float4*)Ln)[i] = ((const float4*)invb)[i];

    // Q tile -> LDS (once): 6 rows x 18 px x 32 c fp16 = 108 cells x 4 chunks
    for (int u = tid; u < 432; u += 256) {
        int cell = u >> 2, ch = u & 3;
        int r = cell / 18, p = cell % 18;
        *(short8*)&Qs[(r * 18 + p) * 32 + ch * 8] =
            *(const short8*)(xb + (((pyb + r) * 98) + (px0 + p)) * 32 + ch * 8);
    }

    f32x4 acc[36];
    #pragma unroll
    for (int i = 0; i < 36; i++) acc[i] = (f32x4)0.f;
    float lacc[4] = {0.f, 0.f, 0.f, 0.f};

    __syncthreads();   // prologue: full drain (Ks[0] DMA + Ln + Qs staged)

    short8 vv[9];

    for (int it = 0; it < 24; ++it) {
        int ly0 = it * 2;
        int cur = it & 1;

        // ---- 1. DMA next Ks (oldest VMEM of this iter — vmcnt(9) relies on it)
        if (it < 23) stage_ks(rb + (ly0 + 2) * 1600, Ks[cur ^ 1], tid);
        // Wall: pin VMEM order (DMA stays oldest); let VALU/MFMA/DS cross so
        // the scheduler can interleave PV(it-1) with this iter's score.
        __builtin_amdgcn_sched_barrier(0x38F);

        // ---- 2. V ks=0 loads (9; ride across the barrier into PV)
        const u16* vit = vw + it * 96;
        #pragma unroll
        for (int nt = 0; nt < 9; ++nt) vv[nt] = *(const short8*)(vit + (size_t)nt * 36864);

        // ---- 3+4. score + exp for both key halves of this wave's q-tile
        const u16* Kc = Ks[cur];
        u16* Pc = Pl[cur];
        #pragma unroll
        for (int kh = 0; kh < 2; ++kh) {
            f32x4 sf[3];
            #pragma unroll
            for (int i = 0; i < 3; i++) sf[i] = (f32x4)0.f;
            __builtin_amdgcn_s_setprio(1);
            #pragma unroll
            for (int ty = 0; ty < 3; ++ty)
                #pragma unroll
                for (int tx = 0; tx < 3; ++tx) {
                    half8 a = *(const half8*)&Qs[((w + ty) * 18 + (l15 + tx)) * 32 + quad * 8];
                    #pragma unroll
                    for (int lxo = 0; lxo < 3; ++lxo) {
                        half8 bb = *(const half8*)&Kc[(kh + ty) * 1600 + (lxo * 16 + l15 + tx) * 32 + quad * 8];
                        sf[lxo] = __builtin_amdgcn_mfma_f32_16x16x32_f16(a, bb, sf[lxo], 0, 0, 0);
                    }
                }
            __builtin_amdgcn_s_setprio(0);
            #pragma unroll
            for (int lxo = 0; lxo < 3; ++lxo) {
                float invs = Ln[(ly0 + kh) * 48 + lxo * 16 + l15];
                int k = kh * 48 + lxo * 16 + l15;
                int kb = k >> 5;
                int kc = (k & 31) ^ (quad << 3);   // XOR swizzle by quad (= m>>2)
                #pragma unroll
                for (int r = 0; r < 4; ++r) {
                    float p = __expf(sf[lxo][r] * invs);
                    u16 h = f2bf(p);
                    Pc[(w * 3 + kb) * 512 + (quad * 4 + r) * 32 + kc] = h;
                    lacc[r] += bf2f(h);   // l exactly as the PV MFMA sees P
                }
            }
        }

        // ---- 5. counted-vmcnt barrier: Pl visible (lgkm 0) + Ks DMA landed
        // (vmcnt<=9: the 9 newer vv loads may stay in flight).
        asm volatile("s_waitcnt vmcnt(9) lgkmcnt(0)" ::: "memory");
        __builtin_amdgcn_s_barrier();
        __builtin_amdgcn_sched_barrier(0);

        // ---- 6. PV: O[64, this wave's 144 cols] += P[64,96] @ V[96,144], bf16
        const u16* Pr = Pl[cur];
        int pcol = l15 * 32 + ((quad ^ (l15 >> 2)) & 3) * 8;
        __builtin_amdgcn_s_setprio(1);
        #pragma unroll
        for (int ks = 0; ks < 3; ++ks) {
            short8 pa0 = *(const short8*)&Pr[(0 * 3 + ks) * 512 + pcol];
            short8 pa1 = *(const short8*)&Pr[(1 * 3 + ks) * 512 + pcol];
            #pragma unroll
            for (int nt = 0; nt < 9; ++nt) {
                short8 vn = vv[nt];
                acc[0 * 9 + nt] = __builtin_amdgcn_mfma_f32_16x16x32_bf16(pa0, vn, acc[0 * 9 + nt], 0, 0, 0);
                acc[1 * 9 + nt] = __builtin_amdgcn_mfma_f32_16x16x32_bf16(pa1, vn, acc[1 * 9 + nt], 0, 0, 0);
            }
            pa0 = *(const short8*)&Pr[(2 * 3 + ks) * 512 + pcol];
            pa1 = *(const short8*)&Pr[(3 * 3 + ks) * 512 + pcol];
            #pragma unroll
            for (int nt = 0; nt < 9; ++nt) {
                short8 vn = vv[nt];
                acc[2 * 9 + nt] = __builtin_amdgcn_mfma_f32_16x16x32_bf16(pa0, vn, acc[2 * 9 + nt], 0, 0, 0);
                acc[3 * 9 + nt] = __builtin_amdgcn_mfma_f32_16x16x32_bf16(pa1, vn, acc[3 * 9 + nt], 0, 0, 0);
                if (ks < 2)   // reload right after last use; covered by rest of phase
                    vv[nt] = *(const short8*)(vit + (size_t)nt * 36864 + (ks + 1) * 32);
            }
        }
        __builtin_amdgcn_s_setprio(0);
    }

    // ---- epilogue: reduce l over l15; share per-tile l via LDS; Z = O/(6l)
    #pragma unroll
    for (int r = 0; r < 4; ++r) {
        float v = lacc[r];
        v += __shfl_xor(v, 1);
        v += __shfl_xor(v, 2);
        v += __shfl_xor(v, 4);
        v += __shfl_xor(v, 8);
        lacc[r] = v;
    }
    if (l15 == 0) {
        #pragma unroll
        for (int r = 0; r < 4; ++r)
            llds[w][quad * 4 + r] = lacc[r];
    }
    __syncthreads();
    float* Zb = Z + (size_t)brel * 9216 * 576;
    #pragma unroll
    for (int mt = 0; mt < 4; ++mt) {
        #pragma unroll
        for (int r = 0; r < 4; ++r) {
            int q = (pyb + mt) * 96 + px0 + quad * 4 + r;
            float rl = 1.0f / (llds[mt][quad * 4 + r] * 6.0f);
            float* zr = Zb + (size_t)q * 576 + w * 144;
            #pragma unroll
            for (int nt = 0; nt < 9; ++nt)
                __builtin_nontemporal_store(acc[mt * 9 + nt][r] * rl, zr + nt * 16 + l15);
        }
    }
}

// ------------------------------------------------------------- gather (Z -> out)
// R7 1-row version (the proven one; 2-row variant was flat-to-negative).
__global__ void kgather(const float* __restrict__ Z, float* __restrict__ out, int b0) {
    __shared__ float zb[2 * 9 * 580];   // 41760 B
    int bi = blockIdx.x;                // nb*96*12
    int brel = bi / (96 * 12);
    int rem = bi % (96 * 12);
    int b = b0 + brel;
    int q = rem / 12, xt = rem % 12;
    int ox0 = xt * 16, p0 = ox0 >> 1;
    const float* Zb = Z + (size_t)brel * 9216 * 576;
    int tid = threadIdx.x;
    for (int id = tid; id < 2592; id += 256) {
        int pi = id / 1296, r2 = id % 1296;
        int pxi = r2 / 144, n4 = r2 % 144;
        int py = q + pi; if (py > 95) py = 95;
        int px = p0 + pxi; if (px > 95) px = 95;
        *(float4*)&zb[(pi * 9 + pxi) * 580 + n4 * 4] =
            *(const float4*)&Zb[(size_t)(py * 96 + px) * 576 + n4 * 4];
    }
    __syncthreads();
    int xi = tid & 15, cq = tid >> 4;
    int ox = ox0 + xi;
    bool oxv = ox <= 190;
    int ntx, txl[2], pxl[2];
    if (xi & 1) { ntx = 2; txl[0] = 0; pxl[0] = (xi + 1) >> 1; txl[1] = 2; pxl[1] = (xi - 1) >> 1; }
    else        { ntx = 1; txl[0] = 1; pxl[0] = xi >> 1; txl[1] = 1; pxl[1] = xi >> 1; }
    int oy0 = 2 * q;
    #pragma unroll
    for (int ck = 0; ck < 4; ++ck) {
        int c = cq + ck * 16;
        float v0 = 0.f, v1 = 0.f;
        for (int j = 0; j < ntx; ++j) {
            int tx = txl[j], pxi = pxl[j];
            v0 += zb[(0 * 9 + pxi) * 580 + (3 + tx) * 64 + c];
            v1 += zb[(1 * 9 + pxi) * 580 + (0 + tx) * 64 + c];
            v1 += zb[(0 * 9 + pxi) * 580 + (6 + tx) * 64 + c];
        }
        if (oxv) {
            float* o = out + (((size_t)(b * 64 + c) * 191 + oy0) * 191 + ox);
            *o = v0;
            if (q < 95) *(o + 191) = v1;
        }
    }
}

// --------------------------------------------------------------------- host
extern "C" void kernel_launch(void* const* d_in, const int* in_sizes, int n_in,
                              void* d_out, int out_size, void* d_ws, size_t ws_size,
                              hipStream_t stream) {
    const float* input = (const float*)d_in[0];
    const float* small = (const float*)d_in[1];
    const float* w1 = (const float*)d_in[2];
    const float* b1 = (const float*)d_in[3];
    const float* a1 = (const float*)d_in[4];
    const float* w2 = (const float*)d_in[5];
    const float* b2 = (const float*)d_in[6];
    const float* a2 = (const float*)d_in[7];
    const float* wa = (const float*)d_in[8];
    const float* ba = (const float*)d_in[9];
    const float* aa = (const float*)d_in[10];

    char* ws = (char*)d_ws;
    u16* xf16 = (u16*)(ws + 0);             //  2,458,624
    u16* rkl = (u16*)(ws + 2458624);        //    640,000
    float* ef = (float*)(ws + 3098624);     //  2,560,000
    u16* vtp = (u16*)(ws + 5658624);        // 10,616,832
    float* invn = (float*)(ws + 16275456);  //     36,864
    const size_t PREP = 16312320;
    float* Zbuf = (float*)(ws + PREP);      // nb*21,233,664
    float* out = (float*)d_out;

    int nb = (ws_size >= (size_t)101246976) ? 4 : 1;

    kzero<<<1024, 256, 0, stream>>>((float4*)ws, 5658624 / 16);   // halo'd arrays
    kmatch<<<384, 256, 0, stream>>>(input, w1, b1, a1, xf16);
    ksmall<<<192, 256, 0, stream>>>(small, wa, ba, aa, w2, b2, a2, ef, rkl);
    kinvnorm<<<36, 256, 0, stream>>>(rkl, invn);
    kvtp<<<192, 256, 0, stream>>>(ef, vtp);

    for (int b0 = 0; b0 < 4; b0 += nb) {
        kfused3<<<nb * 144, 256, 0, stream>>>(xf16, rkl, vtp, invn, Zbuf, b0, nb);
        kgather<<<nb * 1152, 256, 0, stream>>>(Zbuf, out, b0);
    }
}

// Round 10
// 490.664 us; speedup vs baseline: 1.3006x; 1.0776x over previous
//
#include <hip/hip_runtime.h>

// CrossScaleAttention on MI355X — round 15.
// R14 post-mortem: 0x38F wall NEUTRAL, MfmaUtil flat — compiler can't
// interleave across the loop back-edge (different BBs); lever dead.
// Occupancy re-derivation from R6/R9/R10: blocks/CU is LDS-limited
// (47.4KB->19.3%, 66.6KB->15.3%, 96.3KB->13.5%) and co-resident blocks are
// the ONLY latency hider (no pipe >42% busy). 66.56KB allows 2 blocks/CU;
// <53.3KB admits a 3rd (+50% TLP on a latency-bound kernel).
// R15: LDS 66.56 -> 50.9KB, structure untouched:
//  (1) Ks 2x4-row dbuf -> 6-row ring (25.6->19.2KB): stage only the 2 NEW
//      rows/iter (DMA halves, 800->400 chunks). Slot=row%6; staged pair
//      {(2it+4)%6,(2it+5)%6} is contiguous even-aligned; its readers
//      (score(it-1)) drained at the previous barrier. vmcnt(9) unchanged
//      (<=2 DMA ops/wave oldest, 9 V newer).
//  (2) drop Ln (-9.2KB): invs prefetched to 6 regs at iter top, issued
//      BEFORE DMA+V -> exp's in-order wait leaves DMA+V in flight.
// Pre-committed: occ 20-23% & kfused ~300-330 => 3rd block confirmed;
// occ flat ~15% & ~358 => register-capped, next = AGPR cut (BM=48);
// FETCH balloons or >380 => ring/invs bug, revert.
//
// Workspace (101,246,976 B; known-good >= 105.6 MB):
//   xf16 : [4][98][98][32] fp16 match_input, zero halo        2,458,624
//   rkl  : [4][50][50][32] fp16 ref, zero halo                  640,000
//   ef32 : [4][50][50][64] f32 embed_w, zero halo             2,560,000
//   vtp  : [4][576][2304] bf16 V^T (n=tap*64+c, l=ly*48+lx)  10,616,832
//   invn : [4][2304] f32 10/max(norm,1e-4)                       36,864
//   Z    : [nb][9216][576] f32                            nb*21,233,664

typedef unsigned short u16;
typedef __attribute__((ext_vector_type(8))) short short8;      // 8 bf16
typedef __attribute__((ext_vector_type(8))) _Float16 half8;    // 8 fp16
typedef __attribute__((ext_vector_type(4))) float f32x4;

__device__ __forceinline__ u16 f2bf(float f) {
    unsigned u = __float_as_uint(f);
    unsigned r = (u + 0x7FFFu + ((u >> 16) & 1u)) >> 16;   // RNE
    return (u16)r;
}
__device__ __forceinline__ float bf2f(u16 h) {
    return __uint_as_float(((unsigned)h) << 16);
}
__device__ __forceinline__ u16 f2h(float f) {
    _Float16 h = (_Float16)f;           // v_cvt_f16_f32 (RNE)
    u16 u; __builtin_memcpy(&u, &h, 2); return u;
}
__device__ __forceinline__ float h2f(u16 u) {
    _Float16 h; __builtin_memcpy(&h, &u, 2); return (float)h;
}

// ---------------------------------------------------------------- zero fill
__global__ void kzero(float4* p, long n) {
    long i = (long)blockIdx.x * blockDim.x + threadIdx.x;
    long st = (long)gridDim.x * blockDim.x;
    float4 z; z.x = 0.f; z.y = 0.f; z.z = 0.f; z.w = 0.f;
    for (; i < n; i += st) p[i] = z;
}

// ------------------------------------------------- match_input -> xf16
__global__ void kmatch(const float* __restrict__ input, const float* __restrict__ w1,
                       const float* __restrict__ b1, const float* __restrict__ a1,
                       u16* __restrict__ xf16) {
    __shared__ float xl[64 * 96];
    __shared__ float wl[32 * 65];
    int b = blockIdx.x / 96, y = blockIdx.x % 96;
    int tid = threadIdx.x;
    for (int i = tid; i < 64 * 96; i += 256) {
        int ci = i / 96, xx = i % 96;
        xl[i] = input[(((b * 64 + ci) * 96) + y) * 96 + xx];
    }
    for (int i = tid; i < 2048; i += 256) wl[(i >> 6) * 65 + (i & 63)] = w1[i];
    __syncthreads();
    float aa = a1[0];
    for (int o = tid; o < 96 * 32; o += 256) {
        int xx = o >> 5, c = o & 31;
        float acc = b1[c];
        #pragma unroll
        for (int ci = 0; ci < 64; ci++) acc = fmaf(xl[ci * 96 + xx], wl[c * 65 + ci], acc);
        float v = acc >= 0.f ? acc : aa * acc;
        xf16[((b * 98 + y + 1) * 98 + (xx + 1)) * 32 + c] = f2h(v);
    }
}

// --------------------- small -> ef32 (embed, f32) + rkl fp16 (ref)
__global__ void ksmall(const float* __restrict__ small, const float* __restrict__ wasm,
                       const float* __restrict__ basm, const float* __restrict__ aasm,
                       const float* __restrict__ wm2, const float* __restrict__ bm2,
                       const float* __restrict__ am2,
                       float* __restrict__ ef32, u16* __restrict__ rkl) {
    __shared__ float sl[64 * 48];
    __shared__ float wa[64 * 65];
    __shared__ float wm[32 * 65];
    int b = blockIdx.x / 48, y = blockIdx.x % 48;
    int tid = threadIdx.x;
    for (int i = tid; i < 64 * 48; i += 256) {
        int ci = i / 48, xx = i % 48;
        sl[i] = small[(((b * 64 + ci) * 48) + y) * 48 + xx];
    }
    for (int i = tid; i < 4096; i += 256) wa[(i >> 6) * 65 + (i & 63)] = wasm[i];
    for (int i = tid; i < 2048; i += 256) wm[(i >> 6) * 65 + (i & 63)] = wm2[i];
    __syncthreads();
    float ae = aasm[0], ar = am2[0];
    for (int o = tid; o < 48 * 64; o += 256) {            // embed_w
        int xx = o >> 6, c = o & 63;
        float acc = basm[c];
        #pragma unroll
        for (int ci = 0; ci < 64; ci++) acc = fmaf(sl[ci * 48 + xx], wa[c * 65 + ci], acc);
        float v = acc >= 0.f ? acc : ae * acc;
        ef32[((b * 50 + y + 1) * 50 + (xx + 1)) * 64 + c] = v;
    }
    for (int o = tid; o < 48 * 32; o += 256) {            // ref -> rkl fp16
        int xx = o >> 5, c = o & 31;
        float acc = bm2[c];
        #pragma unroll
        for (int ci = 0; ci < 64; ci++) acc = fmaf(sl[ci * 48 + xx], wm[c * 65 + ci], acc);
        float v = acc >= 0.f ? acc : ar * acc;
        rkl[((b * 50 + y + 1) * 50 + (xx + 1)) * 32 + c] = f2h(v);
    }
}

// ------------------------------------------------------------ invnorm per key
__global__ void kinvnorm(const u16* __restrict__ rkl, float* __restrict__ invn) {
    int idx = blockIdx.x * 256 + threadIdx.x;   // 9216 exact
    int b = idx / 2304, l = idx % 2304;
    int ly = l / 48, lx = l % 48;
    float s = 0.f;
    for (int ty = 0; ty < 3; ty++)
        for (int tx = 0; tx < 3; tx++) {
            int base = ((b * 50 + ly + ty) * 50 + (lx + tx)) * 32;
            #pragma unroll
            for (int c = 0; c < 32; c++) {
                float v = h2f(rkl[base + c]);
                s = fmaf(v, v, s);
            }
        }
    invn[idx] = 10.f / fmaxf(sqrtf(s), 1e-4f);   // SCALE folded in
}

// ------------------------------------------------------------- pack V^T bf16
// Block per (b, ly). Stage ef rows ly..ly+2 in LDS (coalesced reads),
// write each n-row's 48-element segment contiguously (coalesced 8B stores).
__global__ void kvtp(const float* __restrict__ ef32, u16* __restrict__ vtp) {
    __shared__ float el[3][50 * 64];    // 38400 B
    int bi = blockIdx.x;                // 4*48
    int b = bi / 48, ly = bi % 48;
    const float* eb = ef32 + (size_t)b * 50 * 50 * 64;
    int tid = threadIdx.x;
    #pragma unroll
    for (int r = 0; r < 3; ++r)
        for (int i = tid; i < 800; i += 256)
            ((float4*)el[r])[i] = ((const float4*)(eb + (size_t)(ly + r) * 3200))[i];
    __syncthreads();
    u16* vo = vtp + (size_t)b * 576 * 2304 + (size_t)ly * 48;
    for (int n = tid; n < 576; n += 256) {
        int t = n >> 6, c = n & 63;
        int ty = t / 3, tx = t - ty * 3;
        u16* dst = vo + (size_t)n * 2304;
        const float* src = &el[ty][tx * 64 + c];
        #pragma unroll
        for (int g = 0; g < 12; ++g) {
            unsigned lo = (unsigned)f2bf(src[(g * 4 + 0) * 64]) |
                          ((unsigned)f2bf(src[(g * 4 + 1) * 64]) << 16);
            unsigned hi = (unsigned)f2bf(src[(g * 4 + 2) * 64]) |
                          ((unsigned)f2bf(src[(g * 4 + 3) * 64]) << 16);
            uint2 pk; pk.x = lo; pk.y = hi;
            *(uint2*)&dst[g * 4] = pk;   // 8B aligned: 2304*2B row stride, 96B base
        }
    }
}

// ---------------------------------------------- async Ks staging
// Prologue: 4 rows = 800 chunks of 16B into ring slots 0..3 (linear).
__device__ __forceinline__ void stage_ks4(const u16* __restrict__ src, u16* dst, int tid) {
    int wb = tid & ~63;   // wave-uniform LDS base
    #pragma unroll
    for (int k = 0; k < 3; ++k)
        __builtin_amdgcn_global_load_lds(
            (const __attribute__((address_space(1))) void*)(src + (size_t)(tid + k * 256) * 8),
            (__attribute__((address_space(3))) void*)(dst + (size_t)(wb + k * 256) * 8),
            16, 0, 0);
    if (tid < 32)   // tail: chunks 768..799
        __builtin_amdgcn_global_load_lds(
            (const __attribute__((address_space(1))) void*)(src + (size_t)(tid + 768) * 8),
            (__attribute__((address_space(3))) void*)(dst + (size_t)768 * 8),
            16, 0, 0);
}
// Steady state: 2 new rows = 400 chunks into a contiguous 2-slot ring block.
__device__ __forceinline__ void stage_ks2(const u16* __restrict__ src, u16* dst, int tid) {
    int wb = tid & ~63;
    __builtin_amdgcn_global_load_lds(
        (const __attribute__((address_space(1))) void*)(src + (size_t)tid * 8),
        (__attribute__((address_space(3))) void*)(dst + (size_t)wb * 8),
        16, 0, 0);
    if (tid < 144)   // chunks 256..399 (waves 0-2 partial; wave 3 skips)
        __builtin_amdgcn_global_load_lds(
            (const __attribute__((address_space(1))) void*)(src + (size_t)(tid + 256) * 8),
            (__attribute__((address_space(3))) void*)(dst + (size_t)(wb + 256) * 8),
            16, 0, 0);
}

// ------------------------------------------------------------- fused score+PV
// grid = nb*144; block = 256 (4 waves). BM=64 queries (4 py-rows x 16 px),
// BN=96 keys/iter, 24 iters. Wave w: score for q-tile w (both key halves),
// PV for n-quarter w over all 64 q (acc[4][9]). Q tile in LDS. One counted
// vmcnt barrier per iter (vmcnt(9): drains Ks DMA, keeps 9 V in flight).
// R15: Ks = 6-row ring (slot = row%6), invs from global (reg-prefetched,
// oldest VMEM of the iter so its wait leaves DMA+V in flight).
__launch_bounds__(256, 2)
__global__ void kfused3(const u16* __restrict__ xf16, const u16* __restrict__ rkl,
                        const u16* __restrict__ vtp, const float* __restrict__ invn,
                        float* __restrict__ Z, int b0, int nb) {
    __shared__ u16 Ks[6][1600];     // 19200 B ring: row r of rkl -> slot r%6
    __shared__ u16 Pl[2][6144];     // 24576 B: dbuf, [4 mtile][3 kb][16 m][32 kc]
    __shared__ u16 Qs[6 * 18 * 32]; //  6912 B: Q tile rows pyb..pyb+5, px0..px0+17
    __shared__ float llds[4][16];   //   256 B  -> 50944 B total (3 blocks/CU)

    int tid = threadIdx.x;
    int w = tid >> 6, lane = tid & 63, l15 = lane & 15, quad = lane >> 4;
    int bi = blockIdx.x, brel, t;
    if (nb == 4) { brel = bi & 3; t = bi >> 2; }
    else         { brel = 0; t = bi; }
    int b = b0 + brel;
    int px0 = (t % 6) * 16, pyb = (t / 6) * 4;     // 6 x-tiles x 24 y-groups = 144

    const u16* xb = xf16 + (size_t)b * 98 * 98 * 32;
    const u16* rb = rkl + (size_t)b * 50 * 50 * 32;
    const float* invb = invn + b * 2304;
    const u16* vw = vtp + (size_t)b * 576 * 2304 + (size_t)(w * 144 + l15) * 2304 + quad * 8;

    stage_ks4(rb, &Ks[0][0], tid);  // rows 0..3 -> slots 0..3; drained at prologue barrier
    __builtin_amdgcn_sched_barrier(0);

    // Q tile -> LDS (once): 6 rows x 18 px x 32 c fp16 = 108 cells x 4 chunks
    for (int u = tid; u < 432; u += 256) {
        int cell = u >> 2, ch = u & 3;
        int r = cell / 18, p = cell % 18;
        *(short8*)&Qs[(r * 18 + p) * 32 + ch * 8] =
            *(const short8*)(xb + (((pyb + r) * 98) + (px0 + p)) * 32 + ch * 8);
    }

    f32x4 acc[36];
    #pragma unroll
    for (int i = 0; i < 36; i++) acc[i] = (f32x4)0.f;
    float lacc[4] = {0.f, 0.f, 0.f, 0.f};

    __syncthreads();   // prologue: full drain (Ks rows 0-3 DMA + Qs staged)

    short8 vv[9];
    int s0 = 0;        // ring slot of row ly0 = (2*it) % 6

    for (int it = 0; it < 24; ++it) {
        int ly0 = it * 2;
        int cur = it & 1;

        // ---- 1. invs prefetch (oldest VMEM: its wait leaves DMA+V in flight)
        float pinv[2][3];
        #pragma unroll
        for (int kh = 0; kh < 2; ++kh)
            #pragma unroll
            for (int lxo = 0; lxo < 3; ++lxo)
                pinv[kh][lxo] = invb[(ly0 + kh) * 48 + lxo * 16 + l15];

        // ---- 2. DMA the 2 NEW rows (ly0+4, ly0+5) into the ring
        if (it < 23) {
            int s4 = s0 + 4; if (s4 >= 6) s4 -= 6;   // slots {s4, s4+1} contiguous
            stage_ks2(rb + (size_t)(ly0 + 4) * 1600, &Ks[0][0] + s4 * 1600, tid);
        }
        // Wall: pin VMEM order (invs/DMA before V); compute/DS may cross.
        __builtin_amdgcn_sched_barrier(0x38F);

        // ---- 3. V ks=0 loads (9; ride across the barrier into PV)
        const u16* vit = vw + it * 96;
        #pragma unroll
        for (int nt = 0; nt < 9; ++nt) vv[nt] = *(const short8*)(vit + (size_t)nt * 36864);

        // ---- 4+5. score + exp for both key halves of this wave's q-tile
        u16* Pc = Pl[cur];
        #pragma unroll
        for (int kh = 0; kh < 2; ++kh) {
            f32x4 sf[3];
            #pragma unroll
            for (int i = 0; i < 3; i++) sf[i] = (f32x4)0.f;
            __builtin_amdgcn_s_setprio(1);
            #pragma unroll
            for (int ty = 0; ty < 3; ++ty) {
                int rr = s0 + kh + ty; if (rr >= 6) rr -= 6;   // ring slot (uniform)
                const u16* Kr = &Ks[0][0] + rr * 1600;
                #pragma unroll
                for (int tx = 0; tx < 3; ++tx) {
                    half8 a = *(const half8*)&Qs[((w + ty) * 18 + (l15 + tx)) * 32 + quad * 8];
                    #pragma unroll
                    for (int lxo = 0; lxo < 3; ++lxo) {
                        half8 bb = *(const half8*)&Kr[(lxo * 16 + l15 + tx) * 32 + quad * 8];
                        sf[lxo] = __builtin_amdgcn_mfma_f32_16x16x32_f16(a, bb, sf[lxo], 0, 0, 0);
                    }
                }
            }
            __builtin_amdgcn_s_setprio(0);
            #pragma unroll
            for (int lxo = 0; lxo < 3; ++lxo) {
                float invs = pinv[kh][lxo];
                int k = kh * 48 + lxo * 16 + l15;
                int kb = k >> 5;
                int kc = (k & 31) ^ (quad << 3);   // XOR swizzle by quad (= m>>2)
                #pragma unroll
                for (int r = 0; r < 4; ++r) {
                    float p = __expf(sf[lxo][r] * invs);
                    u16 h = f2bf(p);
                    Pc[(w * 3 + kb) * 512 + (quad * 4 + r) * 32 + kc] = h;
                    lacc[r] += bf2f(h);   // l exactly as the PV MFMA sees P
                }
            }
        }

        // ---- 6. counted-vmcnt barrier: Pl visible (lgkm 0) + Ks DMA landed
        // (vmcnt<=9: the 9 newer vv loads may stay in flight; invs retired).
        asm volatile("s_waitcnt vmcnt(9) lgkmcnt(0)" ::: "memory");
        __builtin_amdgcn_s_barrier();
        __builtin_amdgcn_sched_barrier(0);

        // ---- 7. PV: O[64, this wave's 144 cols] += P[64,96] @ V[96,144], bf16
        const u16* Pr = Pl[cur];
        int pcol = l15 * 32 + ((quad ^ (l15 >> 2)) & 3) * 8;
        __builtin_amdgcn_s_setprio(1);
        #pragma unroll
        for (int ks = 0; ks < 3; ++ks) {
            short8 pa0 = *(const short8*)&Pr[(0 * 3 + ks) * 512 + pcol];
            short8 pa1 = *(const short8*)&Pr[(1 * 3 + ks) * 512 + pcol];
            #pragma unroll
            for (int nt = 0; nt < 9; ++nt) {
                short8 vn = vv[nt];
                acc[0 * 9 + nt] = __builtin_amdgcn_mfma_f32_16x16x32_bf16(pa0, vn, acc[0 * 9 + nt], 0, 0, 0);
                acc[1 * 9 + nt] = __builtin_amdgcn_mfma_f32_16x16x32_bf16(pa1, vn, acc[1 * 9 + nt], 0, 0, 0);
            }
            pa0 = *(const short8*)&Pr[(2 * 3 + ks) * 512 + pcol];
            pa1 = *(const short8*)&Pr[(3 * 3 + ks) * 512 + pcol];
            #pragma unroll
            for (int nt = 0; nt < 9; ++nt) {
                short8 vn = vv[nt];
                acc[2 * 9 + nt] = __builtin_amdgcn_mfma_f32_16x16x32_bf16(pa0, vn, acc[2 * 9 + nt], 0, 0, 0);
                acc[3 * 9 + nt] = __builtin_amdgcn_mfma_f32_16x16x32_bf16(pa1, vn, acc[3 * 9 + nt], 0, 0, 0);
                if (ks < 2)   // reload right after last use; covered by rest of phase
                    vv[nt] = *(const short8*)(vit + (size_t)nt * 36864 + (ks + 1) * 32);
            }
        }
        __builtin_amdgcn_s_setprio(0);

        s0 += 2; if (s0 >= 6) s0 -= 6;
    }

    // ---- epilogue: reduce l over l15; share per-tile l via LDS; Z = O/(6l)
    #pragma unroll
    for (int r = 0; r < 4; ++r) {
        float v = lacc[r];
        v += __shfl_xor(v, 1);
        v += __shfl_xor(v, 2);
        v += __shfl_xor(v, 4);
        v += __shfl_xor(v, 8);
        lacc[r] = v;
    }
    if (l15 == 0) {
        #pragma unroll
        for (int r = 0; r < 4; ++r)
            llds[w][quad * 4 + r] = lacc[r];
    }
    __syncthreads();
    float* Zb = Z + (size_t)brel * 9216 * 576;
    #pragma unroll
    for (int mt = 0; mt < 4; ++mt) {
        #pragma unroll
        for (int r = 0; r < 4; ++r) {
            int q = (pyb + mt) * 96 + px0 + quad * 4 + r;
            float rl = 1.0f / (llds[mt][quad * 4 + r] * 6.0f);
            float* zr = Zb + (size_t)q * 576 + w * 144;
            #pragma unroll
            for (int nt = 0; nt < 9; ++nt)
                __builtin_nontemporal_store(acc[mt * 9 + nt][r] * rl, zr + nt * 16 + l15);
        }
    }
}

// ------------------------------------------------------------- gather (Z -> out)
// R7 1-row version (the proven one; 2-row variant was flat-to-negative).
__global__ void kgather(const float* __restrict__ Z, float* __restrict__ out, int b0) {
    __shared__ float zb[2 * 9 * 580];   // 41760 B
    int bi = blockIdx.x;                // nb*96*12
    int brel = bi / (96 * 12);
    int rem = bi % (96 * 12);
    int b = b0 + brel;
    int q = rem / 12, xt = rem % 12;
    int ox0 = xt * 16, p0 = ox0 >> 1;
    const float* Zb = Z + (size_t)brel * 9216 * 576;
    int tid = threadIdx.x;
    for (int id = tid; id < 2592; id += 256) {
        int pi = id / 1296, r2 = id % 1296;
        int pxi = r2 / 144, n4 = r2 % 144;
        int py = q + pi; if (py > 95) py = 95;
        int px = p0 + pxi; if (px > 95) px = 95;
        *(float4*)&zb[(pi * 9 + pxi) * 580 + n4 * 4] =
            *(const float4*)&Zb[(size_t)(py * 96 + px) * 576 + n4 * 4];
    }
    __syncthreads();
    int xi = tid & 15, cq = tid >> 4;
    int ox = ox0 + xi;
    bool oxv = ox <= 190;
    int ntx, txl[2], pxl[2];
    if (xi & 1) { ntx = 2; txl[0] = 0; pxl[0] = (xi + 1) >> 1; txl[1] = 2; pxl[1] = (xi - 1) >> 1; }
    else        { ntx = 1; txl[0] = 1; pxl[0] = xi >> 1; txl[1] = 1; pxl[1] = xi >> 1; }
    int oy0 = 2 * q;
    #pragma unroll
    for (int ck = 0; ck < 4; ++ck) {
        int c = cq + ck * 16;
        float v0 = 0.f, v1 = 0.f;
        for (int j = 0; j < ntx; ++j) {
            int tx = txl[j], pxi = pxl[j];
            v0 += zb[(0 * 9 + pxi) * 580 + (3 + tx) * 64 + c];
            v1 += zb[(1 * 9 + pxi) * 580 + (0 + tx) * 64 + c];
            v1 += zb[(0 * 9 + pxi) * 580 + (6 + tx) * 64 + c];
        }
        if (oxv) {
            float* o = out + (((size_t)(b * 64 + c) * 191 + oy0) * 191 + ox);
            *o = v0;
            if (q < 95) *(o + 191) = v1;
        }
    }
}

// --------------------------------------------------------------------- host
extern "C" void kernel_launch(void* const* d_in, const int* in_sizes, int n_in,
                              void* d_out, int out_size, void* d_ws, size_t ws_size,
                              hipStream_t stream) {
    const float* input = (const float*)d_in[0];
    const float* small = (const float*)d_in[1];
    const float* w1 = (const float*)d_in[2];
    const float* b1 = (const float*)d_in[3];
    const float* a1 = (const float*)d_in[4];
    const float* w2 = (const float*)d_in[5];
    const float* b2 = (const float*)d_in[6];
    const float* a2 = (const float*)d_in[7];
    const float* wa = (const float*)d_in[8];
    const float* ba = (const float*)d_in[9];
    const float* aa = (const float*)d_in[10];

    char* ws = (char*)d_ws;
    u16* xf16 = (u16*)(ws + 0);             //  2,458,624
    u16* rkl = (u16*)(ws + 2458624);        //    640,000
    float* ef = (float*)(ws + 3098624);     //  2,560,000
    u16* vtp = (u16*)(ws + 5658624);        // 10,616,832
    float* invn = (float*)(ws + 16275456);  //     36,864
    const size_t PREP = 16312320;
    float* Zbuf = (float*)(ws + PREP);      // nb*21,233,664
    float* out = (float*)d_out;

    int nb = (ws_size >= (size_t)101246976) ? 4 : 1;

    kzero<<<1024, 256, 0, stream>>>((float4*)ws, 5658624 / 16);   // halo'd arrays
    kmatch<<<384, 256, 0, stream>>>(input, w1, b1, a1, xf16);
    ksmall<<<192, 256, 0, stream>>>(small, wa, ba, aa, w2, b2, a2, ef, rkl);
    kinvnorm<<<36, 256, 0, stream>>>(rkl, invn);
    kvtp<<<192, 256, 0, stream>>>(ef, vtp);

    for (int b0 = 0; b0 < 4; b0 += nb) {
        kfused3<<<nb * 144, 256, 0, stream>>>(xf16, rkl, vtp, invn, Zbuf, b0, nb);
        kgather<<<nb * 1152, 256, 0, stream>>>(Zbuf, out, b0);
    }
}

// Round 12
// 471.108 us; speedup vs baseline: 1.3545x; 1.0415x over previous
//
#include <hip/hip_runtime.h>

// CrossScaleAttention on MI355X — round 17 (= R16 resubmit; bench infra
// failed twice, no data — hypothesis untested).
// R15 post-mortem: LDS 66.6->51.2KB but occupancy FELL (15.3->13.4%), dur
// flat 358 -> residency is REGISTER-capped: 128 arch + 144 AGPR (acc[36])
// = 272 unified > 256 = the 2-waves/SIMD boundary under every pool model
// (m69: waves halve at 64/128/256). LDS was never the binder.
// R16/R17: cut acc below the threshold: BM=48 -> per-thread output 108 f32
// -> acc[3][9] = 108 AGPR; unified ~228 <= 256. Under every pool theory
// this strictly raises waves/SIMD (512: 1->2; 768: 2->3; LDS 43.6KB fits
// 3 blocks). Block = 48q x 576n, grid nb*192. Score = 6 half-tasks
// (3 tiles x 2 kh): waves 0/1 own tiles 0/1 (both kh), waves 2/3 split
// tile 2 (27 MFMA each) — imbalance absorbed by the extra co-resident
// waves. Tile-2 l = two wave-partials added in epilogue (reassociation
// ~1e-7, << bf16 tol). P-writes of waves 2/3 hit disjoint (kb,kc).
// Ring Ks / vmcnt(9) / vv prefetch / kvtp / R7 kgather unchanged.
// Pre-committed: occ 19-25% & kfused ~280-320 => reg-cap confirmed;
// occ up & dur flat => latency theory dies, ablation probe; occ flat =>
// quantum model wrong, ablation probe; FETCH >15MB => spill, revert.
//
// Workspace (101,246,976 B; known-good >= 105.6 MB):
//   xf16 : [4][98][98][32] fp16 match_input, zero halo        2,458,624
//   rkl  : [4][50][50][32] fp16 ref, zero halo                  640,000
//   ef32 : [4][50][50][64] f32 embed_w, zero halo             2,560,000
//   vtp  : [4][576][2304] bf16 V^T (n=tap*64+c, l=ly*48+lx)  10,616,832
//   invn : [4][2304] f32 10/max(norm,1e-4)                       36,864
//   Z    : [nb][9216][576] f32                            nb*21,233,664

typedef unsigned short u16;
typedef __attribute__((ext_vector_type(8))) short short8;      // 8 bf16
typedef __attribute__((ext_vector_type(8))) _Float16 half8;    // 8 fp16
typedef __attribute__((ext_vector_type(4))) float f32x4;

__device__ __forceinline__ u16 f2bf(float f) {
    unsigned u = __float_as_uint(f);
    unsigned r = (u + 0x7FFFu + ((u >> 16) & 1u)) >> 16;   // RNE
    return (u16)r;
}
__device__ __forceinline__ float bf2f(u16 h) {
    return __uint_as_float(((unsigned)h) << 16);
}
__device__ __forceinline__ u16 f2h(float f) {
    _Float16 h = (_Float16)f;           // v_cvt_f16_f32 (RNE)
    u16 u; __builtin_memcpy(&u, &h, 2); return u;
}
__device__ __forceinline__ float h2f(u16 u) {
    _Float16 h; __builtin_memcpy(&h, &u, 2); return (float)h;
}

// ---------------------------------------------------------------- zero fill
__global__ void kzero(float4* p, long n) {
    long i = (long)blockIdx.x * blockDim.x + threadIdx.x;
    long st = (long)gridDim.x * blockDim.x;
    float4 z; z.x = 0.f; z.y = 0.f; z.z = 0.f; z.w = 0.f;
    for (; i < n; i += st) p[i] = z;
}

// ------------------------------------------------- match_input -> xf16
__global__ void kmatch(const float* __restrict__ input, const float* __restrict__ w1,
                       const float* __restrict__ b1, const float* __restrict__ a1,
                       u16* __restrict__ xf16) {
    __shared__ float xl[64 * 96];
    __shared__ float wl[32 * 65];
    int b = blockIdx.x / 96, y = blockIdx.x % 96;
    int tid = threadIdx.x;
    for (int i = tid; i < 64 * 96; i += 256) {
        int ci = i / 96, xx = i % 96;
        xl[i] = input[(((b * 64 + ci) * 96) + y) * 96 + xx];
    }
    for (int i = tid; i < 2048; i += 256) wl[(i >> 6) * 65 + (i & 63)] = w1[i];
    __syncthreads();
    float aa = a1[0];
    for (int o = tid; o < 96 * 32; o += 256) {
        int xx = o >> 5, c = o & 31;
        float acc = b1[c];
        #pragma unroll
        for (int ci = 0; ci < 64; ci++) acc = fmaf(xl[ci * 96 + xx], wl[c * 65 + ci], acc);
        float v = acc >= 0.f ? acc : aa * acc;
        xf16[((b * 98 + y + 1) * 98 + (xx + 1)) * 32 + c] = f2h(v);
    }
}

// --------------------- small -> ef32 (embed, f32) + rkl fp16 (ref)
__global__ void ksmall(const float* __restrict__ small, const float* __restrict__ wasm,
                       const float* __restrict__ basm, const float* __restrict__ aasm,
                       const float* __restrict__ wm2, const float* __restrict__ bm2,
                       const float* __restrict__ am2,
                       float* __restrict__ ef32, u16* __restrict__ rkl) {
    __shared__ float sl[64 * 48];
    __shared__ float wa[64 * 65];
    __shared__ float wm[32 * 65];
    int b = blockIdx.x / 48, y = blockIdx.x % 48;
    int tid = threadIdx.x;
    for (int i = tid; i < 64 * 48; i += 256) {
        int ci = i / 48, xx = i % 48;
        sl[i] = small[(((b * 64 + ci) * 48) + y) * 48 + xx];
    }
    for (int i = tid; i < 4096; i += 256) wa[(i >> 6) * 65 + (i & 63)] = wasm[i];
    for (int i = tid; i < 2048; i += 256) wm[(i >> 6) * 65 + (i & 63)] = wm2[i];
    __syncthreads();
    float ae = aasm[0], ar = am2[0];
    for (int o = tid; o < 48 * 64; o += 256) {            // embed_w
        int xx = o >> 6, c = o & 63;
        float acc = basm[c];
        #pragma unroll
        for (int ci = 0; ci < 64; ci++) acc = fmaf(sl[ci * 48 + xx], wa[c * 65 + ci], acc);
        float v = acc >= 0.f ? acc : ae * acc;
        ef32[((b * 50 + y + 1) * 50 + (xx + 1)) * 64 + c] = v;
    }
    for (int o = tid; o < 48 * 32; o += 256) {            // ref -> rkl fp16
        int xx = o >> 5, c = o & 31;
        float acc = bm2[c];
        #pragma unroll
        for (int ci = 0; ci < 64; ci++) acc = fmaf(sl[ci * 48 + xx], wm[c * 65 + ci], acc);
        float v = acc >= 0.f ? acc : ar * acc;
        rkl[((b * 50 + y + 1) * 50 + (xx + 1)) * 32 + c] = f2h(v);
    }
}

// ------------------------------------------------------------ invnorm per key
__global__ void kinvnorm(const u16* __restrict__ rkl, float* __restrict__ invn) {
    int idx = blockIdx.x * 256 + threadIdx.x;   // 9216 exact
    int b = idx / 2304, l = idx % 2304;
    int ly = l / 48, lx = l % 48;
    float s = 0.f;
    for (int ty = 0; ty < 3; ty++)
        for (int tx = 0; tx < 3; tx++) {
            int base = ((b * 50 + ly + ty) * 50 + (lx + tx)) * 32;
            #pragma unroll
            for (int c = 0; c < 32; c++) {
                float v = h2f(rkl[base + c]);
                s = fmaf(v, v, s);
            }
        }
    invn[idx] = 10.f / fmaxf(sqrtf(s), 1e-4f);   // SCALE folded in
}

// ------------------------------------------------------------- pack V^T bf16
// Block per (b, ly). Stage ef rows ly..ly+2 in LDS (coalesced reads),
// write each n-row's 48-element segment contiguously (coalesced 8B stores).
__global__ void kvtp(const float* __restrict__ ef32, u16* __restrict__ vtp) {
    __shared__ float el[3][50 * 64];    // 38400 B
    int bi = blockIdx.x;                // 4*48
    int b = bi / 48, ly = bi % 48;
    const float* eb = ef32 + (size_t)b * 50 * 50 * 64;
    int tid = threadIdx.x;
    #pragma unroll
    for (int r = 0; r < 3; ++r)
        for (int i = tid; i < 800; i += 256)
            ((float4*)el[r])[i] = ((const float4*)(eb + (size_t)(ly + r) * 3200))[i];
    __syncthreads();
    u16* vo = vtp + (size_t)b * 576 * 2304 + (size_t)ly * 48;
    for (int n = tid; n < 576; n += 256) {
        int t = n >> 6, c = n & 63;
        int ty = t / 3, tx = t - ty * 3;
        u16* dst = vo + (size_t)n * 2304;
        const float* src = &el[ty][tx * 64 + c];
        #pragma unroll
        for (int g = 0; g < 12; ++g) {
            unsigned lo = (unsigned)f2bf(src[(g * 4 + 0) * 64]) |
                          ((unsigned)f2bf(src[(g * 4 + 1) * 64]) << 16);
            unsigned hi = (unsigned)f2bf(src[(g * 4 + 2) * 64]) |
                          ((unsigned)f2bf(src[(g * 4 + 3) * 64]) << 16);
            uint2 pk; pk.x = lo; pk.y = hi;
            *(uint2*)&dst[g * 4] = pk;   // 8B aligned: 2304*2B row stride, 96B base
        }
    }
}

// ---------------------------------------------- async Ks staging
// Prologue: 4 rows = 800 chunks of 16B into ring slots 0..3 (linear).
__device__ __forceinline__ void stage_ks4(const u16* __restrict__ src, u16* dst, int tid) {
    int wb = tid & ~63;   // wave-uniform LDS base
    #pragma unroll
    for (int k = 0; k < 3; ++k)
        __builtin_amdgcn_global_load_lds(
            (const __attribute__((address_space(1))) void*)(src + (size_t)(tid + k * 256) * 8),
            (__attribute__((address_space(3))) void*)(dst + (size_t)(wb + k * 256) * 8),
            16, 0, 0);
    if (tid < 32)   // tail: chunks 768..799
        __builtin_amdgcn_global_load_lds(
            (const __attribute__((address_space(1))) void*)(src + (size_t)(tid + 768) * 8),
            (__attribute__((address_space(3))) void*)(dst + (size_t)768 * 8),
            16, 0, 0);
}
// Steady state: 2 new rows = 400 chunks into a contiguous 2-slot ring block.
__device__ __forceinline__ void stage_ks2(const u16* __restrict__ src, u16* dst, int tid) {
    int wb = tid & ~63;
    __builtin_amdgcn_global_load_lds(
        (const __attribute__((address_space(1))) void*)(src + (size_t)tid * 8),
        (__attribute__((address_space(3))) void*)(dst + (size_t)wb * 8),
        16, 0, 0);
    if (tid < 144)   // chunks 256..399 (waves 0-2 partial; wave 3 skips)
        __builtin_amdgcn_global_load_lds(
            (const __attribute__((address_space(1))) void*)(src + (size_t)(tid + 256) * 8),
            (__attribute__((address_space(3))) void*)(dst + (size_t)(wb + 256) * 8),
            16, 0, 0);
}

// ------------------------------------------------------------- fused score+PV
// grid = nb*192; block = 256 (4 waves). BM=48 queries (3 py-rows x 16 px),
// BN=96 keys/iter, 24 iters. Score tasks (tile,kh): wave0=tile0 both kh,
// wave1=tile1 both kh, wave2=tile2 kh0, wave3=tile2 kh1. PV: wave w owns
// n-quarter w over all 48 q (acc[3][9] = 108 AGPR -> ~228 unified regs).
// Ks = 6-row ring; one counted-vmcnt barrier per iter (vmcnt(9)).
__launch_bounds__(256, 2)
__global__ void kfused3(const u16* __restrict__ xf16, const u16* __restrict__ rkl,
                        const u16* __restrict__ vtp, const float* __restrict__ invn,
                        float* __restrict__ Z, int b0, int nb) {
    __shared__ u16 Ks[6][1600];     // 19200 B ring: row r of rkl -> slot r%6
    __shared__ u16 Pl[2][4608];     // 18432 B: dbuf, [3 mtile][3 kb][16 m][32 kc]
    __shared__ u16 Qs[5 * 18 * 32]; //  5760 B: Q rows pyb..pyb+4, px0..px0+17
    __shared__ float llds[4][16];   //   256 B  -> 43648 B total

    int tid = threadIdx.x;
    int w = tid >> 6, lane = tid & 63, l15 = lane & 15, quad = lane >> 4;
    int bi = blockIdx.x, brel, t;
    if (nb == 4) { brel = bi & 3; t = bi >> 2; }
    else         { brel = 0; t = bi; }
    int b = b0 + brel;
    int px0 = (t % 6) * 16, pyb = (t / 6) * 3;     // 6 x-tiles x 32 y-groups = 192

    const u16* xb = xf16 + (size_t)b * 98 * 98 * 32;
    const u16* rb = rkl + (size_t)b * 50 * 50 * 32;
    const float* invb = invn + b * 2304;
    const u16* vw = vtp + (size_t)b * 576 * 2304 + (size_t)(w * 144 + l15) * 2304 + quad * 8;

    stage_ks4(rb, &Ks[0][0], tid);  // rows 0..3 -> slots 0..3; drained at prologue barrier
    __builtin_amdgcn_sched_barrier(0);

    // Q tile -> LDS (once): 5 rows x 18 px x 32 c fp16 = 90 cells x 4 chunks
    for (int u = tid; u < 360; u += 256) {
        int cell = u >> 2, ch = u & 3;
        int r = cell / 18, p = cell % 18;
        *(short8*)&Qs[(r * 18 + p) * 32 + ch * 8] =
            *(const short8*)(xb + (((pyb + r) * 98) + (px0 + p)) * 32 + ch * 8);
    }

    // score task assignment (wave-uniform)
    int tile = (w < 3) ? w : 2;
    int kh_begin = (w == 3) ? 1 : 0;
    int kh_end   = (w == 2) ? 1 : 2;

    f32x4 acc[27];
    #pragma unroll
    for (int i = 0; i < 27; i++) acc[i] = (f32x4)0.f;
    float lacc[4] = {0.f, 0.f, 0.f, 0.f};

    __syncthreads();   // prologue: full drain (Ks rows 0-3 DMA + Qs staged)

    short8 vv[9];
    int s0 = 0;        // ring slot of row ly0 = (2*it) % 6

    for (int it = 0; it < 24; ++it) {
        int ly0 = it * 2;
        int cur = it & 1;

        // ---- 1. invs prefetch (oldest VMEM: its wait leaves DMA+V in flight)
        float pinv[2][3];
        #pragma unroll
        for (int kh = 0; kh < 2; ++kh)
            #pragma unroll
            for (int lxo = 0; lxo < 3; ++lxo)
                pinv[kh][lxo] = invb[(ly0 + kh) * 48 + lxo * 16 + l15];

        // ---- 2. DMA the 2 NEW rows (ly0+4, ly0+5) into the ring
        if (it < 23) {
            int s4 = s0 + 4; if (s4 >= 6) s4 -= 6;   // slots {s4, s4+1} contiguous
            stage_ks2(rb + (size_t)(ly0 + 4) * 1600, &Ks[0][0] + s4 * 1600, tid);
        }
        // Wall: pin VMEM order (invs/DMA before V); compute/DS may cross.
        __builtin_amdgcn_sched_barrier(0x38F);

        // ---- 3. V ks=0 loads (9; ride across the barrier into PV)
        const u16* vit = vw + it * 96;
        #pragma unroll
        for (int nt = 0; nt < 9; ++nt) vv[nt] = *(const short8*)(vit + (size_t)nt * 36864);

        // ---- 4+5. score + exp for this wave's (tile, kh) tasks
        u16* Pc = Pl[cur];
        #pragma unroll
        for (int kh = 0; kh < 2; ++kh) {
            if (kh < kh_begin || kh >= kh_end) continue;   // wave-uniform
            f32x4 sf[3];
            #pragma unroll
            for (int i = 0; i < 3; i++) sf[i] = (f32x4)0.f;
            __builtin_amdgcn_s_setprio(1);
            #pragma unroll
            for (int ty = 0; ty < 3; ++ty) {
                int rr = s0 + kh + ty; if (rr >= 6) rr -= 6;   // ring slot (uniform)
                const u16* Kr = &Ks[0][0] + rr * 1600;
                #pragma unroll
                for (int tx = 0; tx < 3; ++tx) {
                    half8 a = *(const half8*)&Qs[((tile + ty) * 18 + (l15 + tx)) * 32 + quad * 8];
                    #pragma unroll
                    for (int lxo = 0; lxo < 3; ++lxo) {
                        half8 bb = *(const half8*)&Kr[(lxo * 16 + l15 + tx) * 32 + quad * 8];
                        sf[lxo] = __builtin_amdgcn_mfma_f32_16x16x32_f16(a, bb, sf[lxo], 0, 0, 0);
                    }
                }
            }
            __builtin_amdgcn_s_setprio(0);
            #pragma unroll
            for (int lxo = 0; lxo < 3; ++lxo) {
                float invs = pinv[kh][lxo];
                int k = kh * 48 + lxo * 16 + l15;
                int kb = k >> 5;
                int kc = (k & 31) ^ (quad << 3);   // XOR swizzle by quad (= m>>2)
                #pragma unroll
                for (int r = 0; r < 4; ++r) {
                    float p = __expf(sf[lxo][r] * invs);
                    u16 h = f2bf(p);
                    Pc[(tile * 3 + kb) * 512 + (quad * 4 + r) * 32 + kc] = h;
                    lacc[r] += bf2f(h);   // l exactly as the PV MFMA sees P
                }
            }
        }

        // ---- 6. counted-vmcnt barrier: Pl visible (lgkm 0) + Ks DMA landed
        // (vmcnt<=9: the 9 newer vv loads may stay in flight; invs retired).
        asm volatile("s_waitcnt vmcnt(9) lgkmcnt(0)" ::: "memory");
        __builtin_amdgcn_s_barrier();
        __builtin_amdgcn_sched_barrier(0);

        // ---- 7. PV: O[48, this wave's 144 cols] += P[48,96] @ V[96,144], bf16
        const u16* Pr = Pl[cur];
        int pcol = l15 * 32 + ((quad ^ (l15 >> 2)) & 3) * 8;
        __builtin_amdgcn_s_setprio(1);
        #pragma unroll
        for (int ks = 0; ks < 3; ++ks) {
            short8 pa0 = *(const short8*)&Pr[(0 * 3 + ks) * 512 + pcol];
            short8 pa1 = *(const short8*)&Pr[(1 * 3 + ks) * 512 + pcol];
            short8 pa2 = *(const short8*)&Pr[(2 * 3 + ks) * 512 + pcol];
            #pragma unroll
            for (int nt = 0; nt < 9; ++nt) {
                short8 vn = vv[nt];
                acc[0 * 9 + nt] = __builtin_amdgcn_mfma_f32_16x16x32_bf16(pa0, vn, acc[0 * 9 + nt], 0, 0, 0);
                acc[1 * 9 + nt] = __builtin_amdgcn_mfma_f32_16x16x32_bf16(pa1, vn, acc[1 * 9 + nt], 0, 0, 0);
                acc[2 * 9 + nt] = __builtin_amdgcn_mfma_f32_16x16x32_bf16(pa2, vn, acc[2 * 9 + nt], 0, 0, 0);
                if (ks < 2)   // reload right after last use; covered by rest of phase
                    vv[nt] = *(const short8*)(vit + (size_t)nt * 36864 + (ks + 1) * 32);
            }
        }
        __builtin_amdgcn_s_setprio(0);

        s0 += 2; if (s0 >= 6) s0 -= 6;
    }

    // ---- epilogue: reduce l over l15; share per-wave l via LDS; Z = O/(6l)
    // llds[w] = wave w's partial l. Tile l: t0=llds[0], t1=llds[1],
    // t2=llds[2]+llds[3] (waves 2/3 hold kh0/kh1 halves).
    #pragma unroll
    for (int r = 0; r < 4; ++r) {
        float v = lacc[r];
        v += __shfl_xor(v, 1);
        v += __shfl_xor(v, 2);
        v += __shfl_xor(v, 4);
        v += __shfl_xor(v, 8);
        lacc[r] = v;
    }
    if (l15 == 0) {
        #pragma unroll
        for (int r = 0; r < 4; ++r)
            llds[w][quad * 4 + r] = lacc[r];
    }
    __syncthreads();
    float* Zb = Z + (size_t)brel * 9216 * 576;
    #pragma unroll
    for (int mt = 0; mt < 3; ++mt) {
        #pragma unroll
        for (int r = 0; r < 4; ++r) {
            int q = (pyb + mt) * 96 + px0 + quad * 4 + r;
            float lsum = (mt < 2) ? llds[mt][quad * 4 + r]
                                  : (llds[2][quad * 4 + r] + llds[3][quad * 4 + r]);
            float rl = 1.0f / (lsum * 6.0f);
            float* zr = Zb + (size_t)q * 576 + w * 144;
            #pragma unroll
            for (int nt = 0; nt < 9; ++nt)
                __builtin_nontemporal_store(acc[mt * 9 + nt][r] * rl, zr + nt * 16 + l15);
        }
    }
}

// ------------------------------------------------------------- gather (Z -> out)
// R7 1-row version (the proven one; 2-row variant was flat-to-negative).
__global__ void kgather(const float* __restrict__ Z, float* __restrict__ out, int b0) {
    __shared__ float zb[2 * 9 * 580];   // 41760 B
    int bi = blockIdx.x;                // nb*96*12
    int brel = bi / (96 * 12);
    int rem = bi % (96 * 12);
    int b = b0 + brel;
    int q = rem / 12, xt = rem % 12;
    int ox0 = xt * 16, p0 = ox0 >> 1;
    const float* Zb = Z + (size_t)brel * 9216 * 576;
    int tid = threadIdx.x;
    for (int id = tid; id < 2592; id += 256) {
        int pi = id / 1296, r2 = id % 1296;
        int pxi = r2 / 144, n4 = r2 % 144;
        int py = q + pi; if (py > 95) py = 95;
        int px = p0 + pxi; if (px > 95) px = 95;
        *(float4*)&zb[(pi * 9 + pxi) * 580 + n4 * 4] =
            *(const float4*)&Zb[(size_t)(py * 96 + px) * 576 + n4 * 4];
    }
    __syncthreads();
    int xi = tid & 15, cq = tid >> 4;
    int ox = ox0 + xi;
    bool oxv = ox <= 190;
    int ntx, txl[2], pxl[2];
    if (xi & 1) { ntx = 2; txl[0] = 0; pxl[0] = (xi + 1) >> 1; txl[1] = 2; pxl[1] = (xi - 1) >> 1; }
    else        { ntx = 1; txl[0] = 1; pxl[0] = xi >> 1; txl[1] = 1; pxl[1] = xi >> 1; }
    int oy0 = 2 * q;
    #pragma unroll
    for (int ck = 0; ck < 4; ++ck) {
        int c = cq + ck * 16;
        float v0 = 0.f, v1 = 0.f;
        for (int j = 0; j < ntx; ++j) {
            int tx = txl[j], pxi = pxl[j];
            v0 += zb[(0 * 9 + pxi) * 580 + (3 + tx) * 64 + c];
            v1 += zb[(1 * 9 + pxi) * 580 + (0 + tx) * 64 + c];
            v1 += zb[(0 * 9 + pxi) * 580 + (6 + tx) * 64 + c];
        }
        if (oxv) {
            float* o = out + (((size_t)(b * 64 + c) * 191 + oy0) * 191 + ox);
            *o = v0;
            if (q < 95) *(o + 191) = v1;
        }
    }
}

// --------------------------------------------------------------------- host
extern "C" void kernel_launch(void* const* d_in, const int* in_sizes, int n_in,
                              void* d_out, int out_size, void* d_ws, size_t ws_size,
                              hipStream_t stream) {
    const float* input = (const float*)d_in[0];
    const float* small = (const float*)d_in[1];
    const float* w1 = (const float*)d_in[2];
    const float* b1 = (const float*)d_in[3];
    const float* a1 = (const float*)d_in[4];
    const float* w2 = (const float*)d_in[5];
    const float* b2 = (const float*)d_in[6];
    const float* a2 = (const float*)d_in[7];
    const float* wa = (const float*)d_in[8];
    const float* ba = (const float*)d_in[9];
    const float* aa = (const float*)d_in[10];

    char* ws = (char*)d_ws;
    u16* xf16 = (u16*)(ws + 0);             //  2,458,624
    u16* rkl = (u16*)(ws + 2458624);        //    640,000
    float* ef = (float*)(ws + 3098624);     //  2,560,000
    u16* vtp = (u16*)(ws + 5658624);        // 10,616,832
    float* invn = (float*)(ws + 16275456);  //     36,864
    const size_t PREP = 16312320;
    float* Zbuf = (float*)(ws + PREP);      // nb*21,233,664
    float* out = (float*)d_out;

    int nb = (ws_size >= (size_t)101246976) ? 4 : 1;

    kzero<<<1024, 256, 0, stream>>>((float4*)ws, 5658624 / 16);   // halo'd arrays
    kmatch<<<384, 256, 0, stream>>>(input, w1, b1, a1, xf16);
    ksmall<<<192, 256, 0, stream>>>(small, wa, ba, aa, w2, b2, a2, ef, rkl);
    kinvnorm<<<36, 256, 0, stream>>>(rkl, invn);
    kvtp<<<192, 256, 0, stream>>>(ef, vtp);

    for (int b0 = 0; b0 < 4; b0 += nb) {
        kfused3<<<nb * 192, 256, 0, stream>>>(xf16, rkl, vtp, invn, Zbuf, b0, nb);
        kgather<<<nb * 1152, 256, 0, stream>>>(Zbuf, out, b0);
    }
}

// Round 13
// 463.599 us; speedup vs baseline: 1.3765x; 1.0162x over previous
//
#include <hip/hip_runtime.h>

// CrossScaleAttention on MI355X — round 18.
// R17 post-mortem: reg-cap CONFIRMED (220 unified -> 8 waves/CU, occ
// 13.4->18.7, 358->304us). Series insight (R6/R9/R17): per-block-ITER slot
// ~20Kcy regardless of BM -> all gains came from FEWER iterations. ~5Kcy
// of that is fixed per-iter cost (barrier drains, latency edges, exp).
// R18: BN=192 (4 key rows/iter, 12 iters) — halves the fixed-cost count:
//  - acc stays [3][9] (108 AGPR), regs ~unchanged -> 8 waves preserved
//  - score = 12 tasks (3 tiles x 4 kh); wave w owns kh=w for all 3 tiles
//    (81 MFMA/wave/iter, perfectly balanced; pinv only for own kh: 3 regs)
//  - Ks = 10-row ring (6 current rows ly0..ly0+5 + 4 prefetch ly0+6..+9,
//    staged as two even-aligned 2-row chunks; staged slot's last reader
//    drained at previous iter's lgkmcnt(0)+barrier)
//  - Pl = [2][9216] (3 tiles x 6 kb); PV = 6 ks steps, same rolling vv[9]
//  - l: lacc[3][4] per-tile; llds[4][3][16]; epilogue sums over waves
// LDS 75.4KB -> 2 blocks/CU (150.8 < 160). vmcnt(9) audit: outstanding at
// barrier = 3 pinv + <=4 DMA + 9 V = 16 -> wait-to-9 drains pinv+DMA,
// keeps 9 V in flight.
// Pre-committed: kfused ~230-265 => fixed-cost model confirmed; >=300 &
// clean => model wrong (pure LDS-pipe), attack LDS ops next; FETCH >15MB
// => spill, revert R17.
//
// Workspace (101,246,976 B; known-good >= 105.6 MB):
//   xf16 : [4][98][98][32] fp16 match_input, zero halo        2,458,624
//   rkl  : [4][50][50][32] fp16 ref, zero halo                  640,000
//   ef32 : [4][50][50][64] f32 embed_w, zero halo             2,560,000
//   vtp  : [4][576][2304] bf16 V^T (n=tap*64+c, l=ly*48+lx)  10,616,832
//   invn : [4][2304] f32 10/max(norm,1e-4)                       36,864
//   Z    : [nb][9216][576] f32                            nb*21,233,664

typedef unsigned short u16;
typedef __attribute__((ext_vector_type(8))) short short8;      // 8 bf16
typedef __attribute__((ext_vector_type(8))) _Float16 half8;    // 8 fp16
typedef __attribute__((ext_vector_type(4))) float f32x4;

__device__ __forceinline__ u16 f2bf(float f) {
    unsigned u = __float_as_uint(f);
    unsigned r = (u + 0x7FFFu + ((u >> 16) & 1u)) >> 16;   // RNE
    return (u16)r;
}
__device__ __forceinline__ float bf2f(u16 h) {
    return __uint_as_float(((unsigned)h) << 16);
}
__device__ __forceinline__ u16 f2h(float f) {
    _Float16 h = (_Float16)f;           // v_cvt_f16_f32 (RNE)
    u16 u; __builtin_memcpy(&u, &h, 2); return u;
}
__device__ __forceinline__ float h2f(u16 u) {
    _Float16 h; __builtin_memcpy(&h, &u, 2); return (float)h;
}

// ---------------------------------------------------------------- zero fill
__global__ void kzero(float4* p, long n) {
    long i = (long)blockIdx.x * blockDim.x + threadIdx.x;
    long st = (long)gridDim.x * blockDim.x;
    float4 z; z.x = 0.f; z.y = 0.f; z.z = 0.f; z.w = 0.f;
    for (; i < n; i += st) p[i] = z;
}

// ------------------------------------------------- match_input -> xf16
__global__ void kmatch(const float* __restrict__ input, const float* __restrict__ w1,
                       const float* __restrict__ b1, const float* __restrict__ a1,
                       u16* __restrict__ xf16) {
    __shared__ float xl[64 * 96];
    __shared__ float wl[32 * 65];
    int b = blockIdx.x / 96, y = blockIdx.x % 96;
    int tid = threadIdx.x;
    for (int i = tid; i < 64 * 96; i += 256) {
        int ci = i / 96, xx = i % 96;
        xl[i] = input[(((b * 64 + ci) * 96) + y) * 96 + xx];
    }
    for (int i = tid; i < 2048; i += 256) wl[(i >> 6) * 65 + (i & 63)] = w1[i];
    __syncthreads();
    float aa = a1[0];
    for (int o = tid; o < 96 * 32; o += 256) {
        int xx = o >> 5, c = o & 31;
        float acc = b1[c];
        #pragma unroll
        for (int ci = 0; ci < 64; ci++) acc = fmaf(xl[ci * 96 + xx], wl[c * 65 + ci], acc);
        float v = acc >= 0.f ? acc : aa * acc;
        xf16[((b * 98 + y + 1) * 98 + (xx + 1)) * 32 + c] = f2h(v);
    }
}

// --------------------- small -> ef32 (embed, f32) + rkl fp16 (ref)
__global__ void ksmall(const float* __restrict__ small, const float* __restrict__ wasm,
                       const float* __restrict__ basm, const float* __restrict__ aasm,
                       const float* __restrict__ wm2, const float* __restrict__ bm2,
                       const float* __restrict__ am2,
                       float* __restrict__ ef32, u16* __restrict__ rkl) {
    __shared__ float sl[64 * 48];
    __shared__ float wa[64 * 65];
    __shared__ float wm[32 * 65];
    int b = blockIdx.x / 48, y = blockIdx.x % 48;
    int tid = threadIdx.x;
    for (int i = tid; i < 64 * 48; i += 256) {
        int ci = i / 48, xx = i % 48;
        sl[i] = small[(((b * 64 + ci) * 48) + y) * 48 + xx];
    }
    for (int i = tid; i < 4096; i += 256) wa[(i >> 6) * 65 + (i & 63)] = wasm[i];
    for (int i = tid; i < 2048; i += 256) wm[(i >> 6) * 65 + (i & 63)] = wm2[i];
    __syncthreads();
    float ae = aasm[0], ar = am2[0];
    for (int o = tid; o < 48 * 64; o += 256) {            // embed_w
        int xx = o >> 6, c = o & 63;
        float acc = basm[c];
        #pragma unroll
        for (int ci = 0; ci < 64; ci++) acc = fmaf(sl[ci * 48 + xx], wa[c * 65 + ci], acc);
        float v = acc >= 0.f ? acc : ae * acc;
        ef32[((b * 50 + y + 1) * 50 + (xx + 1)) * 64 + c] = v;
    }
    for (int o = tid; o < 48 * 32; o += 256) {            // ref -> rkl fp16
        int xx = o >> 5, c = o & 31;
        float acc = bm2[c];
        #pragma unroll
        for (int ci = 0; ci < 64; ci++) acc = fmaf(sl[ci * 48 + xx], wm[c * 65 + ci], acc);
        float v = acc >= 0.f ? acc : ar * acc;
        rkl[((b * 50 + y + 1) * 50 + (xx + 1)) * 32 + c] = f2h(v);
    }
}

// ------------------------------------------------------------ invnorm per key
__global__ void kinvnorm(const u16* __restrict__ rkl, float* __restrict__ invn) {
    int idx = blockIdx.x * 256 + threadIdx.x;   // 9216 exact
    int b = idx / 2304, l = idx % 2304;
    int ly = l / 48, lx = l % 48;
    float s = 0.f;
    for (int ty = 0; ty < 3; ty++)
        for (int tx = 0; tx < 3; tx++) {
            int base = ((b * 50 + ly + ty) * 50 + (lx + tx)) * 32;
            #pragma unroll
            for (int c = 0; c < 32; c++) {
                float v = h2f(rkl[base + c]);
                s = fmaf(v, v, s);
            }
        }
    invn[idx] = 10.f / fmaxf(sqrtf(s), 1e-4f);   // SCALE folded in
}

// ------------------------------------------------------------- pack V^T bf16
// Block per (b, ly). Stage ef rows ly..ly+2 in LDS (coalesced reads),
// write each n-row's 48-element segment contiguously (coalesced 8B stores).
__global__ void kvtp(const float* __restrict__ ef32, u16* __restrict__ vtp) {
    __shared__ float el[3][50 * 64];    // 38400 B
    int bi = blockIdx.x;                // 4*48
    int b = bi / 48, ly = bi % 48;
    const float* eb = ef32 + (size_t)b * 50 * 50 * 64;
    int tid = threadIdx.x;
    #pragma unroll
    for (int r = 0; r < 3; ++r)
        for (int i = tid; i < 800; i += 256)
            ((float4*)el[r])[i] = ((const float4*)(eb + (size_t)(ly + r) * 3200))[i];
    __syncthreads();
    u16* vo = vtp + (size_t)b * 576 * 2304 + (size_t)ly * 48;
    for (int n = tid; n < 576; n += 256) {
        int t = n >> 6, c = n & 63;
        int ty = t / 3, tx = t - ty * 3;
        u16* dst = vo + (size_t)n * 2304;
        const float* src = &el[ty][tx * 64 + c];
        #pragma unroll
        for (int g = 0; g < 12; ++g) {
            unsigned lo = (unsigned)f2bf(src[(g * 4 + 0) * 64]) |
                          ((unsigned)f2bf(src[(g * 4 + 1) * 64]) << 16);
            unsigned hi = (unsigned)f2bf(src[(g * 4 + 2) * 64]) |
                          ((unsigned)f2bf(src[(g * 4 + 3) * 64]) << 16);
            uint2 pk; pk.x = lo; pk.y = hi;
            *(uint2*)&dst[g * 4] = pk;   // 8B aligned: 2304*2B row stride, 96B base
        }
    }
}

// ---------------------------------------------- async Ks staging
// 4 rows = 800 chunks of 16B (linear).
__device__ __forceinline__ void stage_ks4(const u16* __restrict__ src, u16* dst, int tid) {
    int wb = tid & ~63;   // wave-uniform LDS base
    #pragma unroll
    for (int k = 0; k < 3; ++k)
        __builtin_amdgcn_global_load_lds(
            (const __attribute__((address_space(1))) void*)(src + (size_t)(tid + k * 256) * 8),
            (__attribute__((address_space(3))) void*)(dst + (size_t)(wb + k * 256) * 8),
            16, 0, 0);
    if (tid < 32)   // tail: chunks 768..799
        __builtin_amdgcn_global_load_lds(
            (const __attribute__((address_space(1))) void*)(src + (size_t)(tid + 768) * 8),
            (__attribute__((address_space(3))) void*)(dst + (size_t)768 * 8),
            16, 0, 0);
}
// 2 rows = 400 chunks into a contiguous 2-slot ring block.
__device__ __forceinline__ void stage_ks2(const u16* __restrict__ src, u16* dst, int tid) {
    int wb = tid & ~63;
    __builtin_amdgcn_global_load_lds(
        (const __attribute__((address_space(1))) void*)(src + (size_t)tid * 8),
        (__attribute__((address_space(3))) void*)(dst + (size_t)wb * 8),
        16, 0, 0);
    if (tid < 144)   // chunks 256..399
        __builtin_amdgcn_global_load_lds(
            (const __attribute__((address_space(1))) void*)(src + (size_t)(tid + 256) * 8),
            (__attribute__((address_space(3))) void*)(dst + (size_t)(wb + 256) * 8),
            16, 0, 0);
}

// ------------------------------------------------------------- fused score+PV
// grid = nb*192; block = 256 (4 waves). BM=48 queries (3 py-rows x 16 px),
// BN=192 keys/iter (4 key rows), 12 iters. Score: wave w owns kh=w for all
// 3 tiles (3 tasks x 27 MFMA, balanced). PV: wave w owns n-quarter w over
// all 48 q: 6 ks x 3 mt x 9 nt (acc[3][9] = 108 AGPR, ~220 unified).
// Ks = 10-row ring; one counted-vmcnt barrier per iter (vmcnt(9)).
__launch_bounds__(256, 2)
__global__ void kfused3(const u16* __restrict__ xf16, const u16* __restrict__ rkl,
                        const u16* __restrict__ vtp, const float* __restrict__ invn,
                        float* __restrict__ Z, int b0, int nb) {
    __shared__ u16 Ks[10][1600];     // 32000 B ring: rkl row r -> slot r%10
    __shared__ u16 Pl[2][9216];      // 36864 B: dbuf, [3 mtile][6 kb][16 m][32 kc]
    __shared__ u16 Qs[5 * 18 * 32];  //  5760 B: Q rows pyb..pyb+4, px0..px0+17
    __shared__ float llds[4][3][16]; //   768 B  -> 75392 B total (2 blocks/CU)

    int tid = threadIdx.x;
    int w = tid >> 6, lane = tid & 63, l15 = lane & 15, quad = lane >> 4;
    int bi = blockIdx.x, brel, t;
    if (nb == 4) { brel = bi & 3; t = bi >> 2; }   // bi%8 fixes XCD: 1 batch per XCD
    else         { brel = 0; t = bi; }
    int b = b0 + brel;
    int px0 = (t % 6) * 16, pyb = (t / 6) * 3;     // 6 x-tiles x 32 y-groups = 192

    const u16* xb = xf16 + (size_t)b * 98 * 98 * 32;
    const u16* rb = rkl + (size_t)b * 50 * 50 * 32;
    const float* invb = invn + b * 2304;
    const u16* vw = vtp + (size_t)b * 576 * 2304 + (size_t)(w * 144 + l15) * 2304 + quad * 8;

    stage_ks4(rb, &Ks[0][0], tid);                    // rows 0..3 -> slots 0..3
    stage_ks2(rb + (size_t)4 * 1600, &Ks[4][0], tid); // rows 4,5 -> slots 4,5
    __builtin_amdgcn_sched_barrier(0);

    // Q tile -> LDS (once): 5 rows x 18 px x 32 c fp16 = 90 cells x 4 chunks
    for (int u = tid; u < 360; u += 256) {
        int cell = u >> 2, ch = u & 3;
        int r = cell / 18, p = cell % 18;
        *(short8*)&Qs[(r * 18 + p) * 32 + ch * 8] =
            *(const short8*)(xb + (((pyb + r) * 98) + (px0 + p)) * 32 + ch * 8);
    }

    f32x4 acc[27];
    #pragma unroll
    for (int i = 0; i < 27; i++) acc[i] = (f32x4)0.f;
    float lacc[3][4];
    #pragma unroll
    for (int i = 0; i < 3; i++)
        #pragma unroll
        for (int r = 0; r < 4; r++) lacc[i][r] = 0.f;

    __syncthreads();   // prologue: full drain (Ks rows 0-5 DMA + Qs staged)

    short8 vv[9];
    int s0 = 0;        // ring slot of row ly0 = (4*it) % 10

    for (int it = 0; it < 12; ++it) {
        int ly0 = it * 4;
        int cur = it & 1;

        // ---- 1. invs prefetch for THIS wave's kh=w (oldest VMEM this iter)
        float pinv[3];
        #pragma unroll
        for (int lxo = 0; lxo < 3; ++lxo)
            pinv[lxo] = invb[(ly0 + w) * 48 + lxo * 16 + l15];

        // ---- 2. DMA the 4 NEW rows (ly0+6..ly0+9) as two 2-row chunks
        if (it < 11) {
            int s6 = s0 + 6; if (s6 >= 10) s6 -= 10;
            int s8 = s0 + 8; if (s8 >= 10) s8 -= 10;
            stage_ks2(rb + (size_t)(ly0 + 6) * 1600, &Ks[0][0] + s6 * 1600, tid);
            stage_ks2(rb + (size_t)(ly0 + 8) * 1600, &Ks[0][0] + s8 * 1600, tid);
        }
        // Wall: pin VMEM order (invs/DMA before V); compute/DS may cross.
        __builtin_amdgcn_sched_barrier(0x38F);

        // ---- 3. V ks=0 loads (9; ride across the barrier into PV)
        const u16* vit = vw + it * 192;
        #pragma unroll
        for (int nt = 0; nt < 9; ++nt) vv[nt] = *(const short8*)(vit + (size_t)nt * 36864);

        // ---- 4+5. score + exp: this wave's kh=w, tiles 0..2
        u16* Pc = Pl[cur];
        #pragma unroll
        for (int tile = 0; tile < 3; ++tile) {
            f32x4 sf[3];
            #pragma unroll
            for (int i = 0; i < 3; i++) sf[i] = (f32x4)0.f;
            __builtin_amdgcn_s_setprio(1);
            #pragma unroll
            for (int ty = 0; ty < 3; ++ty) {
                int rr = s0 + w + ty; if (rr >= 10) rr -= 10;   // ring slot (uniform)
                const u16* Kr = &Ks[0][0] + rr * 1600;
                #pragma unroll
                for (int tx = 0; tx < 3; ++tx) {
                    half8 a = *(const half8*)&Qs[((tile + ty) * 18 + (l15 + tx)) * 32 + quad * 8];
                    #pragma unroll
                    for (int lxo = 0; lxo < 3; ++lxo) {
                        half8 bb = *(const half8*)&Kr[(lxo * 16 + l15 + tx) * 32 + quad * 8];
                        sf[lxo] = __builtin_amdgcn_mfma_f32_16x16x32_f16(a, bb, sf[lxo], 0, 0, 0);
                    }
                }
            }
            __builtin_amdgcn_s_setprio(0);
            #pragma unroll
            for (int lxo = 0; lxo < 3; ++lxo) {
                float invs = pinv[lxo];
                int k = w * 48 + lxo * 16 + l15;        // key index in 0..191
                int kb = k >> 5;
                int kc = (k & 31) ^ (quad << 3);        // XOR swizzle by quad
                #pragma unroll
                for (int r = 0; r < 4; ++r) {
                    float p = __expf(sf[lxo][r] * invs);
                    u16 h = f2bf(p);
                    Pc[(tile * 6 + kb) * 512 + (quad * 4 + r) * 32 + kc] = h;
                    lacc[tile][r] += bf2f(h);   // l exactly as the PV MFMA sees P
                }
            }
        }

        // ---- 6. counted-vmcnt barrier: Pl visible (lgkm 0) + Ks DMA landed
        // (outstanding = 3 pinv + <=4 DMA + 9 V = 16; wait-to-9 drains
        // pinv+DMA, keeps the 9 V loads in flight).
        asm volatile("s_waitcnt vmcnt(9) lgkmcnt(0)" ::: "memory");
        __builtin_amdgcn_s_barrier();
        __builtin_amdgcn_sched_barrier(0);

        // ---- 7. PV: O[48, this wave's 144 cols] += P[48,192] @ V[192,144]
        const u16* Pr = Pl[cur];
        int pcol = l15 * 32 + ((quad ^ (l15 >> 2)) & 3) * 8;
        __builtin_amdgcn_s_setprio(1);
        #pragma unroll
        for (int ks = 0; ks < 6; ++ks) {
            short8 pa0 = *(const short8*)&Pr[(0 * 6 + ks) * 512 + pcol];
            short8 pa1 = *(const short8*)&Pr[(1 * 6 + ks) * 512 + pcol];
            short8 pa2 = *(const short8*)&Pr[(2 * 6 + ks) * 512 + pcol];
            #pragma unroll
            for (int nt = 0; nt < 9; ++nt) {
                short8 vn = vv[nt];
                acc[0 * 9 + nt] = __builtin_amdgcn_mfma_f32_16x16x32_bf16(pa0, vn, acc[0 * 9 + nt], 0, 0, 0);
                acc[1 * 9 + nt] = __builtin_amdgcn_mfma_f32_16x16x32_bf16(pa1, vn, acc[1 * 9 + nt], 0, 0, 0);
                acc[2 * 9 + nt] = __builtin_amdgcn_mfma_f32_16x16x32_bf16(pa2, vn, acc[2 * 9 + nt], 0, 0, 0);
                if (ks < 5)   // reload right after last use; covered by rest of phase
                    vv[nt] = *(const short8*)(vit + (size_t)nt * 36864 + (ks + 1) * 32);
            }
        }
        __builtin_amdgcn_s_setprio(0);

        s0 += 4; if (s0 >= 10) s0 -= 10;
    }

    // ---- epilogue: reduce l over l15; per-wave per-tile partials via LDS;
    // tile l = sum over waves (each wave held kh=w). Z = O/(6l).
    #pragma unroll
    for (int tile = 0; tile < 3; ++tile)
        #pragma unroll
        for (int r = 0; r < 4; ++r) {
            float v = lacc[tile][r];
            v += __shfl_xor(v, 1);
            v += __shfl_xor(v, 2);
            v += __shfl_xor(v, 4);
            v += __shfl_xor(v, 8);
            lacc[tile][r] = v;
        }
    if (l15 == 0) {
        #pragma unroll
        for (int tile = 0; tile < 3; ++tile)
            #pragma unroll
            for (int r = 0; r < 4; ++r)
                llds[w][tile][quad * 4 + r] = lacc[tile][r];
    }
    __syncthreads();
    float* Zb = Z + (size_t)brel * 9216 * 576;
    #pragma unroll
    for (int mt = 0; mt < 3; ++mt) {
        #pragma unroll
        for (int r = 0; r < 4; ++r) {
            int q = (pyb + mt) * 96 + px0 + quad * 4 + r;
            int m = quad * 4 + r;
            float lsum = llds[0][mt][m] + llds[1][mt][m] + llds[2][mt][m] + llds[3][mt][m];
            float rl = 1.0f / (lsum * 6.0f);
            float* zr = Zb + (size_t)q * 576 + w * 144;
            #pragma unroll
            for (int nt = 0; nt < 9; ++nt)
                __builtin_nontemporal_store(acc[mt * 9 + nt][r] * rl, zr + nt * 16 + l15);
        }
    }
}

// ------------------------------------------------------------- gather (Z -> out)
// R7 1-row version (the proven one; 2-row variant was flat-to-negative).
__global__ void kgather(const float* __restrict__ Z, float* __restrict__ out, int b0) {
    __shared__ float zb[2 * 9 * 580];   // 41760 B
    int bi = blockIdx.x;                // nb*96*12
    int brel = bi / (96 * 12);
    int rem = bi % (96 * 12);
    int b = b0 + brel;
    int q = rem / 12, xt = rem % 12;
    int ox0 = xt * 16, p0 = ox0 >> 1;
    const float* Zb = Z + (size_t)brel * 9216 * 576;
    int tid = threadIdx.x;
    for (int id = tid; id < 2592; id += 256) {
        int pi = id / 1296, r2 = id % 1296;
        int pxi = r2 / 144, n4 = r2 % 144;
        int py = q + pi; if (py > 95) py = 95;
        int px = p0 + pxi; if (px > 95) px = 95;
        *(float4*)&zb[(pi * 9 + pxi) * 580 + n4 * 4] =
            *(const float4*)&Zb[(size_t)(py * 96 + px) * 576 + n4 * 4];
    }
    __syncthreads();
    int xi = tid & 15, cq = tid >> 4;
    int ox = ox0 + xi;
    bool oxv = ox <= 190;
    int ntx, txl[2], pxl[2];
    if (xi & 1) { ntx = 2; txl[0] = 0; pxl[0] = (xi + 1) >> 1; txl[1] = 2; pxl[1] = (xi - 1) >> 1; }
    else        { ntx = 1; txl[0] = 1; pxl[0] = xi >> 1; txl[1] = 1; pxl[1] = xi >> 1; }
    int oy0 = 2 * q;
    #pragma unroll
    for (int ck = 0; ck < 4; ++ck) {
        int c = cq + ck * 16;
        float v0 = 0.f, v1 = 0.f;
        for (int j = 0; j < ntx; ++j) {
            int tx = txl[j], pxi = pxl[j];
            v0 += zb[(0 * 9 + pxi) * 580 + (3 + tx) * 64 + c];
            v1 += zb[(1 * 9 + pxi) * 580 + (0 + tx) * 64 + c];
            v1 += zb[(0 * 9 + pxi) * 580 + (6 + tx) * 64 + c];
        }
        if (oxv) {
            float* o = out + (((size_t)(b * 64 + c) * 191 + oy0) * 191 + ox);
            *o = v0;
            if (q < 95) *(o + 191) = v1;
        }
    }
}

// --------------------------------------------------------------------- host
extern "C" void kernel_launch(void* const* d_in, const int* in_sizes, int n_in,
                              void* d_out, int out_size, void* d_ws, size_t ws_size,
                              hipStream_t stream) {
    const float* input = (const float*)d_in[0];
    const float* small = (const float*)d_in[1];
    const float* w1 = (const float*)d_in[2];
    const float* b1 = (const float*)d_in[3];
    const float* a1 = (const float*)d_in[4];
    const float* w2 = (const float*)d_in[5];
    const float* b2 = (const float*)d_in[6];
    const float* a2 = (const float*)d_in[7];
    const float* wa = (const float*)d_in[8];
    const float* ba = (const float*)d_in[9];
    const float* aa = (const float*)d_in[10];

    char* ws = (char*)d_ws;
    u16* xf16 = (u16*)(ws + 0);             //  2,458,624
    u16* rkl = (u16*)(ws + 2458624);        //    640,000
    float* ef = (float*)(ws + 3098624);     //  2,560,000
    u16* vtp = (u16*)(ws + 5658624);        // 10,616,832
    float* invn = (float*)(ws + 16275456);  //     36,864
    const size_t PREP = 16312320;
    float* Zbuf = (float*)(ws + PREP);      // nb*21,233,664
    float* out = (float*)d_out;

    int nb = (ws_size >= (size_t)101246976) ? 4 : 1;

    kzero<<<1024, 256, 0, stream>>>((float4*)ws, 5658624 / 16);   // halo'd arrays
    kmatch<<<384, 256, 0, stream>>>(input, w1, b1, a1, xf16);
    ksmall<<<192, 256, 0, stream>>>(small, wa, ba, aa, w2, b2, a2, ef, rkl);
    kinvnorm<<<36, 256, 0, stream>>>(rkl, invn);
    kvtp<<<192, 256, 0, stream>>>(ef, vtp);

    for (int b0 = 0; b0 < 4; b0 += nb) {
        kfused3<<<nb * 192, 256, 0, stream>>>(xf16, rkl, vtp, invn, Zbuf, b0, nb);
        kgather<<<nb * 1152, 256, 0, stream>>>(Zbuf, out, b0);
    }
}